// Round 5
// baseline (929.303 us; speedup 1.0000x reference)
//
#include <hip/hip_runtime.h>
#include <hip/hip_bf16.h>
#include <stdint.h>

#define R_ 32
#define H_ 256
#define GAMMA_ 10.0f

typedef __attribute__((ext_vector_type(4))) float f32x4;
typedef __attribute__((ext_vector_type(8))) short bf16x8;

__device__ __forceinline__ unsigned short f2b(float f){
  union { float f; unsigned u; } v; v.f = f;
  unsigned r = v.u + 0x7FFFu + ((v.u >> 16) & 1u);
  return (unsigned short)(r >> 16);
}
__device__ __forceinline__ float b2f(unsigned short h){
  union { unsigned u; float f; } v; v.u = ((unsigned)h) << 16; return v.f;
}

// ---------- fp32 -> bf16 convert (vectorized) ----------
__global__ void cvt_kernel(const float* __restrict__ in, unsigned short* __restrict__ out, int n4){
  int i = blockIdx.x * 256 + threadIdx.x;
  if (i < n4){
    float4 v = ((const float4*)in)[i];
    ushort4 o; o.x=f2b(v.x); o.y=f2b(v.y); o.z=f2b(v.z); o.w=f2b(v.w);
    ((ushort4*)out)[i] = o;
  }
}

// ---------- W[r][i][o] fp32 -> out[r*rstride + o*256 + i] bf16 ([r][n][k]) ----------
__global__ void transw_kernel(const float* __restrict__ W, unsigned short* __restrict__ out, int rstride){
  __shared__ float tile[32][33];
  int r = blockIdx.z;
  int i0 = blockIdx.x * 32, o0 = blockIdx.y * 32;
  const float* Wr = W + (size_t)r * 65536;
  for (int rr = threadIdx.y; rr < 32; rr += 8)
    tile[rr][threadIdx.x] = Wr[(size_t)(i0 + rr) * 256 + o0 + threadIdx.x];
  __syncthreads();
  unsigned short* outr = out + (size_t)r * rstride;
  for (int rr = threadIdx.y; rr < 32; rr += 8)
    outr[(size_t)(o0 + rr) * 256 + i0 + threadIdx.x] = f2b(tile[threadIdx.x][rr]);
}

// ---------- wqkT[i][out]: out<32 -> wq[out][i], out>=32 -> wk[out-32][i] ----------
__global__ void wqk_kernel(const float* __restrict__ W, const float* __restrict__ q,
                           const float* __restrict__ k, float* __restrict__ wqkT){
  int i = blockIdx.x, r = blockIdx.y, lane = threadIdx.x;
  const float* row = W + ((size_t)r * 256 + i) * 256;
  float sq = 0.f, sk = 0.f;
  for (int o = lane; o < 256; o += 64){ float w = row[o]; sq += w * q[r*256+o]; sk += w * k[r*256+o]; }
  #pragma unroll
  for (int off = 32; off; off >>= 1){ sq += __shfl_xor(sq, off); sk += __shfl_xor(sk, off); }
  if (!lane){ wqkT[i * 64 + r] = sq; wqkT[i * 64 + 32 + r] = sk; }
}

// ---------- rel = relu(rel_bert @ rel_lin_w + b) -> bf16 [32][256] ----------
__global__ void rel_kernel(const float* __restrict__ rb, const float* __restrict__ rw,
                           const float* __restrict__ bias, unsigned short* __restrict__ relb){
  int r = blockIdx.x, h = threadIdx.x;
  float acc = bias[h];
  const float* br = rb + (size_t)r * 768;
  for (int i = 0; i < 768; ++i) acc += br[i] * rw[(size_t)i * 256 + h];
  relb[r*256 + h] = f2b(fmaxf(acc, 0.f));
}

// ---------- sorted-edge structure: bin key = (dst>>5)*1024 + et*32 + (dst&31) ----------
__global__ void hist2_kernel(const int* __restrict__ dst, const int* __restrict__ et,
                             int* __restrict__ cnt2, int E){
  int e = blockIdx.x * 256 + threadIdx.x;
  if (e < E){
    int d = dst[e];
    atomicAdd(&cnt2[(d >> 5) * 1024 + et[e] * 32 + (d & 31)], 1);
  }
}
__global__ void totred_kernel(const int* __restrict__ cnt2, int* __restrict__ tot){
  __shared__ int red[256];
  int blk = blockIdx.x, t = threadIdx.x;
  int s = 0;
  #pragma unroll
  for (int q = 0; q < 4; ++q) s += cnt2[blk * 1024 + q * 256 + t];
  red[t] = s; __syncthreads();
  for (int o = 128; o; o >>= 1){ if (t < o) red[t] += red[t + o]; __syncthreads(); }
  if (!t) tot[blk] = red[0];
}
__global__ void scan_kernel(const int* __restrict__ deg, int* __restrict__ off, int n){
  __shared__ int carry;
  __shared__ int buf[1024];
  if (threadIdx.x == 0) carry = 0;
  __syncthreads();
  for (int base = 0; base < n; base += 1024){
    int i = base + threadIdx.x;
    int v = (i < n) ? deg[i] : 0;
    buf[threadIdx.x] = v; __syncthreads();
    for (int o = 1; o < 1024; o <<= 1){
      int t = (threadIdx.x >= o) ? buf[threadIdx.x - o] : 0;
      __syncthreads();
      buf[threadIdx.x] += t;
      __syncthreads();
    }
    if (i < n) off[i] = carry + buf[threadIdx.x] - v;   // exclusive
    __syncthreads();
    if (threadIdx.x == 1023) carry += buf[1023];
    __syncthreads();
  }
  if (threadIdx.x == 0) off[n] = carry;
}
__global__ __launch_bounds__(256) void ps2scan_kernel(const int* __restrict__ cnt2, const int* __restrict__ base,
                                                      int* __restrict__ ps2, int nblk, int nbins){
  __shared__ int sb[1024];
  int blk = blockIdx.x, t = threadIdx.x;
  int orig[4];
  #pragma unroll
  for (int q = 0; q < 4; ++q){ int i = q * 256 + t; orig[q] = cnt2[blk * 1024 + i]; sb[i] = orig[q]; }
  __syncthreads();
  for (int o = 1; o < 1024; o <<= 1){
    int v[4];
    #pragma unroll
    for (int q = 0; q < 4; ++q){ int i = q * 256 + t; v[q] = (i >= o) ? sb[i - o] : 0; }
    __syncthreads();
    #pragma unroll
    for (int q = 0; q < 4; ++q){ int i = q * 256 + t; sb[i] += v[q]; }
    __syncthreads();
  }
  int b = base[blk];
  #pragma unroll
  for (int q = 0; q < 4; ++q){ int i = q * 256 + t; ps2[blk * 1024 + i] = b + sb[i] - orig[q]; }
  if (blk == 0 && t == 0) ps2[nbins] = base[nblk];
}
__global__ void scatter2_kernel(const int* __restrict__ src, const int* __restrict__ dst,
                                const int* __restrict__ et, const int* __restrict__ ps2,
                                int* __restrict__ cur2, int* __restrict__ es_src,
                                int* __restrict__ es_nl, int E){
  int e = blockIdx.x * 256 + threadIdx.x;
  if (e >= E) return;
  int d = dst[e];
  int key = (d >> 5) * 1024 + et[e] * 32 + (d & 31);
  int pos = ps2[key] + atomicAdd(&cur2[key], 1);
  es_src[pos] = src[e];
  es_nl[pos]  = d & 31;
}

// ---------- qdot[n][r], kdot[n][r]: wave per node, lane = output, coalesced wqkT ----------
__global__ void qdot_kernel(const unsigned short* __restrict__ xb, const float* __restrict__ wqkT,
                            float* __restrict__ qdot, float* __restrict__ kdot, int n){
  __shared__ float xrow[4][256];
  int w = threadIdx.x >> 6, lane = threadIdx.x & 63;
  int node = blockIdx.x * 4 + w;
  if (node >= n) return;
  ushort4 v = ((const ushort4*)(xb + (size_t)node * 256))[lane];
  float* xr = xrow[w];
  xr[lane * 4 + 0] = b2f(v.x);
  xr[lane * 4 + 1] = b2f(v.y);
  xr[lane * 4 + 2] = b2f(v.z);
  xr[lane * 4 + 3] = b2f(v.w);
  float acc = 0.f;
  #pragma unroll 8
  for (int kk = 0; kk < 256; ++kk)
    acc = fmaf(xr[kk], wqkT[kk * 64 + lane], acc);
  if (lane < 32) qdot[node * 32 + lane] = acc;
  else           kdot[node * 32 + lane - 32] = acc;
}

// ---------- softmax over in-edges, lane r handles the node's (et=r) run ----------
__global__ void attn2_kernel(const float* __restrict__ qdot, const float* __restrict__ kdot,
                             const int* __restrict__ ps2, const int* __restrict__ es_src,
                             float* __restrict__ a, int n){
  int node = blockIdx.x * 4 + (threadIdx.x >> 6);
  int lane = threadIdx.x & 63;
  if (node >= n) return;
  int s = 0, e = 0;
  float qd = 0.f;
  if (lane < 32){
    int key = (node >> 5) * 1024 + lane * 32 + (node & 31);
    s = ps2[key]; e = ps2[key + 1];
    qd = qdot[node * 32 + lane];
  }
  float m = -1e30f;
  for (int j = s; j < e; ++j){
    float z = qd + kdot[es_src[j] * 32 + lane];
    z = (z > 0.f) ? z : 0.2f * z;          // leaky_relu 0.2
    a[j] = z;
    m = fmaxf(m, z);
  }
  #pragma unroll
  for (int o = 32; o; o >>= 1) m = fmaxf(m, __shfl_xor(m, o));
  float sum = 0.f;
  for (int j = s; j < e; ++j){
    float ez = __expf(a[j] - m);
    a[j] = ez; sum += ez;
  }
  #pragma unroll
  for (int o = 32; o; o >>= 1) sum += __shfl_xor(sum, o);
  float inv = 1.0f / (sum + 1e-16f);
  for (int j = s; j < e; ++j) a[j] *= inv;
}

// ---------- fused aggregate+transform: 32 dst nodes/block, loop over relations ----------
// h[dst] = relu( sum_r g_r[dst] @ W_r ), g_r built in LDS from L2-resident x rows.
__global__ __launch_bounds__(256) void fused_kernel(
    const unsigned short* __restrict__ xb, const unsigned short* __restrict__ Wt,
    const float* __restrict__ a, const int* __restrict__ ps2,
    const int* __restrict__ es_src, const int* __restrict__ es_nl,
    unsigned short* __restrict__ hout, int M){
  __shared__ float glf[32][256];            // 32 KB fp32 accumulate (thread t owns col t)
  __shared__ unsigned short gbf[32 * 256];  // 16 KB bf16, chunk-XOR swizzled
  const int blk = blockIdx.x;
  const int t = threadIdx.x, lane = t & 63, wid = t >> 6;
  const int lg = lane >> 4, lr = lane & 15;
  const int wn = wid * 64;
  const int binbase = blk * 1024;

  f32x4 acc[2][4];
  #pragma unroll
  for (int i = 0; i < 2; ++i)
    #pragma unroll
    for (int j = 0; j < 4; ++j) acc[i][j] = (f32x4)0.0f;

  for (int r = 0; r < 32; ++r){
    // zero + build g_r (column-exclusive: no barrier needed between these)
    #pragma unroll
    for (int i = 0; i < 32; ++i) glf[i][t] = 0.f;
    const int rs = ps2[binbase + r * 32];
    const int re = ps2[binbase + r * 32 + 32];
    int j = rs;
    for (; j + 4 <= re; j += 4){
      int sc0 = es_src[j], sc1 = es_src[j+1], sc2 = es_src[j+2], sc3 = es_src[j+3];
      int n0 = es_nl[j], n1 = es_nl[j+1], n2 = es_nl[j+2], n3 = es_nl[j+3];
      float a0 = a[j], a1 = a[j+1], a2 = a[j+2], a3 = a[j+3];
      unsigned short x0 = xb[(size_t)sc0 * 256 + t];
      unsigned short x1 = xb[(size_t)sc1 * 256 + t];
      unsigned short x2 = xb[(size_t)sc2 * 256 + t];
      unsigned short x3 = xb[(size_t)sc3 * 256 + t];
      glf[n0][t] += a0 * b2f(x0);
      glf[n1][t] += a1 * b2f(x1);
      glf[n2][t] += a2 * b2f(x2);
      glf[n3][t] += a3 * b2f(x3);
    }
    for (; j < re; ++j)
      glf[es_nl[j]][t] += a[j] * b2f(xb[(size_t)es_src[j] * 256 + t]);
    __syncthreads();   // all builds done (also: all waves past prior r's MFMA reads of gbf)
    // convert glf -> swizzled bf16 (row = t>>3; 4 chunks of 8 elems each)
    {
      int row = t >> 3;
      #pragma unroll
      for (int cq = 0; cq < 4; ++cq){
        int c = (t & 7) + cq * 8;
        int cs = c ^ (row & 7);
        float4 v0 = *(const float4*)&glf[row][c * 8];
        float4 v1 = *(const float4*)&glf[row][c * 8 + 4];
        ushort4 o0; o0.x=f2b(v0.x); o0.y=f2b(v0.y); o0.z=f2b(v0.z); o0.w=f2b(v0.w);
        ushort4 o1; o1.x=f2b(v1.x); o1.y=f2b(v1.y); o1.z=f2b(v1.z); o1.w=f2b(v1.w);
        *(ushort4*)&gbf[row * 256 + cs * 8]     = o0;
        *(ushort4*)&gbf[row * 256 + cs * 8 + 4] = o1;
      }
    }
    __syncthreads();   // gbf ready for MFMA
    // MFMA: acc += g_r @ W_r^T ; A from LDS gbf, B streamed from L2 (Wt[r][n][k])
    const unsigned short* Wr = Wt + (size_t)r * 65536;
    bf16x8 bgN[4];
    #pragma unroll
    for (int ni = 0; ni < 4; ++ni)
      bgN[ni] = *(const bf16x8*)&Wr[(size_t)(wn + ni * 16 + lr) * 256 + lg * 8];
    #pragma unroll
    for (int kk = 0; kk < 8; ++kk){
      bf16x8 bg[4];
      #pragma unroll
      for (int ni = 0; ni < 4; ++ni) bg[ni] = bgN[ni];
      if (kk < 7){
        #pragma unroll
        for (int ni = 0; ni < 4; ++ni)
          bgN[ni] = *(const bf16x8*)&Wr[(size_t)(wn + ni * 16 + lr) * 256 + (lg + (kk + 1) * 4) * 8];
      }
      bf16x8 af[2];
      #pragma unroll
      for (int mi = 0; mi < 2; ++mi){
        int row = mi * 16 + lr;
        int c = (lg + kk * 4) ^ (row & 7);
        af[mi] = *(const bf16x8*)&gbf[row * 256 + c * 8];
      }
      #pragma unroll
      for (int mi = 0; mi < 2; ++mi)
        #pragma unroll
        for (int ni = 0; ni < 4; ++ni)
          acc[mi][ni] = __builtin_amdgcn_mfma_f32_16x16x32_bf16(af[mi], bg[ni], acc[mi][ni], 0, 0, 0);
    }
    // no barrier here: next r's glf writes are column-owned; gbf rewrite is
    // guarded by the post-build __syncthreads above.
  }

  // epilogue: C/D layout col=lane&15, row=(lane>>4)*4+reg ; relu
  const int mbase = blk * 32;
  #pragma unroll
  for (int mi = 0; mi < 2; ++mi){
    #pragma unroll
    for (int jj = 0; jj < 4; ++jj){
      int rowm = mbase + mi * 16 + lg * 4 + jj;
      if (rowm >= M) continue;
      #pragma unroll
      for (int ni = 0; ni < 4; ++ni){
        int col = wn + ni * 16 + lr;
        hout[(size_t)rowm * H_ + col] = f2b(fmaxf(acc[mi][ni][jj], 0.f));
      }
    }
  }
}

// ---------- streaming-K MFMA GEMM (final linear): C = A[m][k] . Bk[n][k] + bias ----------
template<int MODE>
__global__ __launch_bounds__(256) void gemm2_kernel(
    const unsigned short* __restrict__ A, const unsigned short* __restrict__ Bk,
    unsigned short* __restrict__ C, const float* __restrict__ bias, int M, int KTOT){
  __shared__ unsigned short As[2][64 * 64];
  __shared__ unsigned short Bs[2][256 * 64];
  const int mbase = blockIdx.x * 64;
  const int tid = threadIdx.x;
  const int lane = tid & 63;
  const int wid  = tid >> 6;
  const int wn = wid * 64;
  const int lg = lane >> 4, lr = lane & 15;

  f32x4 acc[4][4];
  #pragma unroll
  for (int i = 0; i < 4; ++i)
    #pragma unroll
    for (int j = 0; j < 4; ++j) acc[i][j] = (f32x4)0.0f;

  auto stage = [&](int buf, int kt){
    #pragma unroll
    for (int q = 0; q < 2; ++q){
      int ci = q * 256 + tid;
      int row = ci >> 3, p = ci & 7;
      int gch = p ^ (row & 7);
      int grow = mbase + row; if (grow >= M) grow = M - 1;
      const unsigned short* ga = A + (size_t)grow * KTOT + kt * 64 + gch * 8;
      __builtin_amdgcn_global_load_lds((const __attribute__((address_space(1))) void*)ga,
          (__attribute__((address_space(3))) void*)(As[buf] + (size_t)ci * 8), 16, 0, 0);
    }
    #pragma unroll
    for (int q = 0; q < 8; ++q){
      int ci = q * 256 + tid;
      int row = ci >> 3, p = ci & 7;
      int gch = p ^ (row & 7);
      const unsigned short* gb = Bk + (size_t)row * KTOT + kt * 64 + gch * 8;
      __builtin_amdgcn_global_load_lds((const __attribute__((address_space(1))) void*)gb,
          (__attribute__((address_space(3))) void*)(Bs[buf] + (size_t)ci * 8), 16, 0, 0);
    }
  };

  const int nkt = KTOT >> 6;
  stage(0, 0);
  __syncthreads();

  for (int kt = 0; kt < nkt; ++kt){
    const int cur = kt & 1;
    if (kt + 1 < nkt) stage(cur ^ 1, kt + 1);
    #pragma unroll
    for (int kk = 0; kk < 2; ++kk){
      bf16x8 af[4], bg[4];
      #pragma unroll
      for (int mi = 0; mi < 4; ++mi){
        int row = mi * 16 + lr;
        int pc = (lg + kk * 4) ^ (row & 7);
        af[mi] = *(const bf16x8*)&As[cur][row * 64 + pc * 8];
      }
      #pragma unroll
      for (int ni = 0; ni < 4; ++ni){
        int row = wn + ni * 16 + lr;
        int pc = (lg + kk * 4) ^ (row & 7);
        bg[ni] = *(const bf16x8*)&Bs[cur][row * 64 + pc * 8];
      }
      #pragma unroll
      for (int mi = 0; mi < 4; ++mi)
        #pragma unroll
        for (int ni = 0; ni < 4; ++ni)
          acc[mi][ni] = __builtin_amdgcn_mfma_f32_16x16x32_bf16(af[mi], bg[ni], acc[mi][ni], 0, 0, 0);
    }
    __syncthreads();
  }

  #pragma unroll
  for (int mi = 0; mi < 4; ++mi){
    #pragma unroll
    for (int j = 0; j < 4; ++j){
      int rowm = mbase + mi * 16 + lg * 4 + j;
      if (rowm >= M) continue;
      #pragma unroll
      for (int ni = 0; ni < 4; ++ni){
        int col = wn + ni * 16 + lr;
        float v = acc[mi][ni][j];
        if (MODE == 0) C[(size_t)rowm * H_ + col] = f2b(fmaxf(v, 0.f));
        else           C[(size_t)rowm * H_ + col] = f2b(v + bias[col]);
      }
    }
  }
}

// ---------- TransE scoring (wave per edge) ----------
__global__ void score_kernel(const unsigned short* __restrict__ hb, const unsigned short* __restrict__ relb,
                             const int* __restrict__ src_a, const int* __restrict__ dst_a,
                             const int* __restrict__ et_a, float* __restrict__ out, int E){
  int e = blockIdx.x * 4 + (threadIdx.x >> 6);
  int lane = threadIdx.x & 63;
  if (e >= E) return;
  int s = src_a[e], d = dst_a[e], r = et_a[e];
  ushort4 a4 = ((const ushort4*)(hb + (size_t)s * H_))[lane];
  ushort4 b4 = ((const ushort4*)(hb + (size_t)d * H_))[lane];
  ushort4 r4 = ((const ushort4*)(relb + (size_t)r * H_))[lane];
  float sum = fabsf(b2f(a4.x) + b2f(r4.x) - b2f(b4.x))
            + fabsf(b2f(a4.y) + b2f(r4.y) - b2f(b4.y))
            + fabsf(b2f(a4.z) + b2f(r4.z) - b2f(b4.z))
            + fabsf(b2f(a4.w) + b2f(r4.w) - b2f(b4.w));
  #pragma unroll
  for (int o = 32; o; o >>= 1) sum += __shfl_xor(sum, o);
  if (!lane) out[e] = GAMMA_ - sum;
}

extern "C" void kernel_launch(void* const* d_in, const int* in_sizes, int n_in,
                              void* d_out, int out_size, void* d_ws, size_t ws_size,
                              hipStream_t stream){
  const float* x         = (const float*)d_in[0];
  const int*   edge_idx  = (const int*)d_in[1];
  const int*   edge_type = (const int*)d_in[2];
  const float* W1        = (const float*)d_in[3];
  const float* q1        = (const float*)d_in[4];
  const float* k1        = (const float*)d_in[5];
  const float* W2        = (const float*)d_in[6];
  const float* q2        = (const float*)d_in[7];
  const float* k2        = (const float*)d_in[8];
  const float* lin_w     = (const float*)d_in[9];
  const float* lin_b     = (const float*)d_in[10];
  const float* rel_bert  = (const float*)d_in[11];
  const float* rel_lin_w = (const float*)d_in[12];
  const float* rel_lin_b = (const float*)d_in[13];
  float* score = (float*)d_out;

  const int Nn = in_sizes[0] / H_;   // 10000
  const int E  = in_sizes[1] / 2;    // 320000
  const int* src_a = edge_idx;
  const int* dst_a = edge_idx + E;
  const int NBLK  = (Nn + 31) / 32;  // 313
  const int NBINS = NBLK * 1024;

  // workspace carve-up (256B aligned)
  char* ws = (char*)d_ws;
  size_t cur_off = 0;
  auto carve = [&](size_t bytes)->char*{
    char* p = ws + cur_off;
    cur_off += (bytes + 255) & ~(size_t)255;
    return p;
  };
  unsigned short* xb   = (unsigned short*)carve((size_t)Nn * H_ * 2);
  unsigned short* h1   = (unsigned short*)carve((size_t)Nn * H_ * 2);
  unsigned short* h2   = (unsigned short*)carve((size_t)Nn * H_ * 2);
  unsigned short* outb = (unsigned short*)carve((size_t)Nn * H_ * 2);
  unsigned short* Wt1  = (unsigned short*)carve((size_t)R_ * 65536 * 2);
  unsigned short* Wt2  = (unsigned short*)carve((size_t)R_ * 65536 * 2);
  unsigned short* linT = (unsigned short*)carve(65536 * 2);
  unsigned short* relb = (unsigned short*)carve(R_ * H_ * 2);
  float* wqkT1 = (float*)carve(64 * H_ * 4);
  float* wqkT2 = (float*)carve(64 * H_ * 4);
  float* qdot  = (float*)carve((size_t)Nn * R_ * 4);
  float* kdot  = (float*)carve((size_t)Nn * R_ * 4);
  int* cnt2    = (int*)carve((size_t)NBINS * 4);
  int* cur2    = (int*)carve((size_t)NBINS * 4);
  int* tot     = (int*)carve((size_t)NBLK * 4);
  int* baseA   = (int*)carve((size_t)(NBLK + 1) * 4);
  int* ps2     = (int*)carve((size_t)(NBINS + 1) * 4);
  int* es_src  = (int*)carve((size_t)E * 4);
  int* es_nl   = (int*)carve((size_t)E * 4);
  float* attn  = (float*)carve((size_t)E * 4);
  (void)ws_size; (void)n_in; (void)out_size;

  // prep
  cvt_kernel<<<(Nn * H_ / 4 + 255) / 256, 256, 0, stream>>>(x, xb, Nn * H_ / 4);
  transw_kernel<<<dim3(8, 8, R_), dim3(32, 8), 0, stream>>>(W1, Wt1, 65536);
  transw_kernel<<<dim3(8, 8, R_), dim3(32, 8), 0, stream>>>(W2, Wt2, 65536);
  transw_kernel<<<dim3(8, 8, 1),  dim3(32, 8), 0, stream>>>(lin_w, linT, 0);
  wqk_kernel<<<dim3(H_, R_), 64, 0, stream>>>(W1, q1, k1, wqkT1);
  wqk_kernel<<<dim3(H_, R_), 64, 0, stream>>>(W2, q2, k2, wqkT2);
  rel_kernel<<<R_, H_, 0, stream>>>(rel_bert, rel_lin_w, rel_lin_b, relb);

  // sorted-edge structure (shared by both layers)
  hipMemsetAsync(cnt2, 0, (size_t)NBINS * 4, stream);
  hipMemsetAsync(cur2, 0, (size_t)NBINS * 4, stream);
  hist2_kernel<<<(E + 255) / 256, 256, 0, stream>>>(dst_a, edge_type, cnt2, E);
  totred_kernel<<<NBLK, 256, 0, stream>>>(cnt2, tot);
  scan_kernel<<<1, 1024, 0, stream>>>(tot, baseA, NBLK);
  ps2scan_kernel<<<NBLK, 256, 0, stream>>>(cnt2, baseA, ps2, NBLK, NBINS);
  scatter2_kernel<<<(E + 255) / 256, 256, 0, stream>>>(src_a, dst_a, edge_type, ps2, cur2, es_src, es_nl, E);

  // ---- layer 1 ----
  qdot_kernel<<<(Nn + 3) / 4, 256, 0, stream>>>(xb, wqkT1, qdot, kdot, Nn);
  attn2_kernel<<<(Nn + 3) / 4, 256, 0, stream>>>(qdot, kdot, ps2, es_src, attn, Nn);
  fused_kernel<<<NBLK, 256, 0, stream>>>(xb, Wt1, attn, ps2, es_src, es_nl, h1, Nn);

  // ---- layer 2 ----
  qdot_kernel<<<(Nn + 3) / 4, 256, 0, stream>>>(h1, wqkT2, qdot, kdot, Nn);
  attn2_kernel<<<(Nn + 3) / 4, 256, 0, stream>>>(qdot, kdot, ps2, es_src, attn, Nn);
  fused_kernel<<<NBLK, 256, 0, stream>>>(h1, Wt2, attn, ps2, es_src, es_nl, h2, Nn);

  // ---- final linear + scoring ----
  gemm2_kernel<1><<<(Nn + 63) / 64, 256, 0, stream>>>(h2, linT, outb, lin_b, Nn, 256);
  score_kernel<<<(E + 3) / 4, 256, 0, stream>>>(outb, relb, src_a, dst_a, edge_type, score, E);
}

// Round 6
// 433.387 us; speedup vs baseline: 2.1443x; 2.1443x over previous
//
#include <hip/hip_runtime.h>
#include <hip/hip_bf16.h>
#include <stdint.h>

#define R_ 32
#define H_ 256
#define GAMMA_ 10.0f

typedef __attribute__((ext_vector_type(4))) float f32x4;
typedef __attribute__((ext_vector_type(8))) short bf16x8;

__device__ __forceinline__ unsigned short f2b(float f){
  union { float f; unsigned u; } v; v.f = f;
  unsigned r = v.u + 0x7FFFu + ((v.u >> 16) & 1u);
  return (unsigned short)(r >> 16);
}
__device__ __forceinline__ float b2f(unsigned short h){
  union { unsigned u; float f; } v; v.u = ((unsigned)h) << 16; return v.f;
}

// ---------- fp32 -> bf16 convert (vectorized) ----------
__global__ void cvt_kernel(const float* __restrict__ in, unsigned short* __restrict__ out, int n4){
  int i = blockIdx.x * 256 + threadIdx.x;
  if (i < n4){
    float4 v = ((const float4*)in)[i];
    ushort4 o; o.x=f2b(v.x); o.y=f2b(v.y); o.z=f2b(v.z); o.w=f2b(v.w);
    ((ushort4*)out)[i] = o;
  }
}

// ---------- W[r][i][o] fp32 -> out[r*65536 + o*256 + i] bf16 ([r][n][k]) ----------
__global__ void transw_kernel(const float* __restrict__ W, unsigned short* __restrict__ out){
  __shared__ float tile[32][33];
  int r = blockIdx.z;
  int i0 = blockIdx.x * 32, o0 = blockIdx.y * 32;
  const float* Wr = W + (size_t)r * 65536;
  for (int rr = threadIdx.y; rr < 32; rr += 8)
    tile[rr][threadIdx.x] = Wr[(size_t)(i0 + rr) * 256 + o0 + threadIdx.x];
  __syncthreads();
  unsigned short* outr = out + (size_t)r * 65536;
  for (int rr = threadIdx.y; rr < 32; rr += 8)
    outr[(size_t)(o0 + rr) * 256 + i0 + threadIdx.x] = f2b(tile[threadIdx.x][rr]);
}

// ---------- wqkT[i][out]: out<32 -> wq[out][i], out>=32 -> wk[out-32][i] ----------
__global__ void wqk_kernel(const float* __restrict__ W, const float* __restrict__ q,
                           const float* __restrict__ k, float* __restrict__ wqkT){
  int i = blockIdx.x, r = blockIdx.y, lane = threadIdx.x;
  const float* row = W + ((size_t)r * 256 + i) * 256;
  float sq = 0.f, sk = 0.f;
  for (int o = lane; o < 256; o += 64){ float w = row[o]; sq += w * q[r*256+o]; sk += w * k[r*256+o]; }
  #pragma unroll
  for (int off = 32; off; off >>= 1){ sq += __shfl_xor(sq, off); sk += __shfl_xor(sk, off); }
  if (!lane){ wqkT[i * 64 + r] = sq; wqkT[i * 64 + 32 + r] = sk; }
}

// ---------- rel = relu(rel_bert @ rel_lin_w + b) -> bf16 [32][256] ----------
__global__ void rel_kernel(const float* __restrict__ rb, const float* __restrict__ rw,
                           const float* __restrict__ bias, unsigned short* __restrict__ relb){
  int r = blockIdx.x, h = threadIdx.x;
  float acc = bias[h];
  const float* br = rb + (size_t)r * 768;
  for (int i = 0; i < 768; ++i) acc += br[i] * rw[(size_t)i * 256 + h];
  relb[r*256 + h] = f2b(fmaxf(acc, 0.f));
}

// ---------- sorted-edge structure: bin key = (dst>>5)*1024 + (dst&31)*32 + et ----------
// => each node's edges are one contiguous run, et-sorted within the run.
__global__ void hist2_kernel(const int* __restrict__ dst, const int* __restrict__ et,
                             int* __restrict__ cnt2, int E){
  int e = blockIdx.x * 256 + threadIdx.x;
  if (e < E){
    int d = dst[e];
    atomicAdd(&cnt2[(d >> 5) * 1024 + (d & 31) * 32 + et[e]], 1);
  }
}
__global__ void totred_kernel(const int* __restrict__ cnt2, int* __restrict__ tot){
  __shared__ int red[256];
  int blk = blockIdx.x, t = threadIdx.x;
  int s = 0;
  #pragma unroll
  for (int q = 0; q < 4; ++q) s += cnt2[blk * 1024 + q * 256 + t];
  red[t] = s; __syncthreads();
  for (int o = 128; o; o >>= 1){ if (t < o) red[t] += red[t + o]; __syncthreads(); }
  if (!t) tot[blk] = red[0];
}
__global__ void scan_kernel(const int* __restrict__ deg, int* __restrict__ off, int n){
  __shared__ int carry;
  __shared__ int buf[1024];
  if (threadIdx.x == 0) carry = 0;
  __syncthreads();
  for (int base = 0; base < n; base += 1024){
    int i = base + threadIdx.x;
    int v = (i < n) ? deg[i] : 0;
    buf[threadIdx.x] = v; __syncthreads();
    for (int o = 1; o < 1024; o <<= 1){
      int t = (threadIdx.x >= o) ? buf[threadIdx.x - o] : 0;
      __syncthreads();
      buf[threadIdx.x] += t;
      __syncthreads();
    }
    if (i < n) off[i] = carry + buf[threadIdx.x] - v;   // exclusive
    __syncthreads();
    if (threadIdx.x == 1023) carry += buf[1023];
    __syncthreads();
  }
  if (threadIdx.x == 0) off[n] = carry;
}
__global__ __launch_bounds__(256) void ps2scan_kernel(const int* __restrict__ cnt2, const int* __restrict__ base,
                                                      int* __restrict__ ps2, int nblk, int nbins){
  __shared__ int sb[1024];
  int blk = blockIdx.x, t = threadIdx.x;
  int orig[4];
  #pragma unroll
  for (int q = 0; q < 4; ++q){ int i = q * 256 + t; orig[q] = cnt2[blk * 1024 + i]; sb[i] = orig[q]; }
  __syncthreads();
  for (int o = 1; o < 1024; o <<= 1){
    int v[4];
    #pragma unroll
    for (int q = 0; q < 4; ++q){ int i = q * 256 + t; v[q] = (i >= o) ? sb[i - o] : 0; }
    __syncthreads();
    #pragma unroll
    for (int q = 0; q < 4; ++q){ int i = q * 256 + t; sb[i] += v[q]; }
    __syncthreads();
  }
  int b = base[blk];
  #pragma unroll
  for (int q = 0; q < 4; ++q){ int i = q * 256 + t; ps2[blk * 1024 + i] = b + sb[i] - orig[q]; }
  if (blk == 0 && t == 0) ps2[nbins] = base[nblk];
}
__global__ void scatter2_kernel(const int* __restrict__ src, const int* __restrict__ dst,
                                const int* __restrict__ et, const int* __restrict__ ps2,
                                int* __restrict__ cur2, int* __restrict__ es_src,
                                int* __restrict__ es_et, int E){
  int e = blockIdx.x * 256 + threadIdx.x;
  if (e >= E) return;
  int d = dst[e], r = et[e];
  int key = (d >> 5) * 1024 + (d & 31) * 32 + r;
  int pos = ps2[key] + atomicAdd(&cur2[key], 1);
  es_src[pos] = src[e];
  es_et[pos]  = r;
}

// ---------- qdot[n][r], kdot[n][r]: wave per node, lane = output, coalesced wqkT ----------
__global__ void qdot_kernel(const unsigned short* __restrict__ xb, const float* __restrict__ wqkT,
                            float* __restrict__ qdot, float* __restrict__ kdot, int n){
  __shared__ float xrow[4][256];
  int w = threadIdx.x >> 6, lane = threadIdx.x & 63;
  int node = blockIdx.x * 4 + w;
  if (node >= n) return;
  ushort4 v = ((const ushort4*)(xb + (size_t)node * 256))[lane];
  float* xr = xrow[w];
  xr[lane * 4 + 0] = b2f(v.x);
  xr[lane * 4 + 1] = b2f(v.y);
  xr[lane * 4 + 2] = b2f(v.z);
  xr[lane * 4 + 3] = b2f(v.w);
  float acc = 0.f;
  #pragma unroll 8
  for (int kk = 0; kk < 256; ++kk)
    acc = fmaf(xr[kk], wqkT[kk * 64 + lane], acc);
  if (lane < 32) qdot[node * 32 + lane] = acc;
  else           kdot[node * 32 + lane - 32] = acc;
}

// ---------- softmax over in-edges: lane r handles the node's (et=r) run ----------
__global__ void attn2_kernel(const float* __restrict__ qdot, const float* __restrict__ kdot,
                             const int* __restrict__ ps2, const int* __restrict__ es_src,
                             float* __restrict__ a, int n){
  int node = blockIdx.x * 4 + (threadIdx.x >> 6);
  int lane = threadIdx.x & 63;
  if (node >= n) return;
  int s = 0, e = 0;
  float qd = 0.f;
  if (lane < 32){
    int key = (node >> 5) * 1024 + (node & 31) * 32 + lane;
    s = ps2[key]; e = ps2[key + 1];
    qd = qdot[node * 32 + lane];
  }
  float m = -1e30f;
  for (int j = s; j < e; ++j){
    float z = qd + kdot[es_src[j] * 32 + lane];
    z = (z > 0.f) ? z : 0.2f * z;          // leaky_relu 0.2
    a[j] = z;
    m = fmaxf(m, z);
  }
  #pragma unroll
  for (int o = 32; o; o >>= 1) m = fmaxf(m, __shfl_xor(m, o));
  float sum = 0.f;
  for (int j = s; j < e; ++j){
    float ez = __expf(a[j] - m);
    a[j] = ez; sum += ez;
  }
  #pragma unroll
  for (int o = 32; o; o >>= 1) sum += __shfl_xor(sum, o);
  float inv = 1.0f / (sum + 1e-16f);
  for (int j = s; j < e; ++j) a[j] *= inv;
}

// ---------- MFMA bf16 GEMM with double-buffered prefetch (R3-proven) ----------
// A: [M][256] bf16. Bt: [R][256 n][256 k] bf16 (k contiguous).
// MODE 0: C = xt[r][M][256] (r-slice-major!);  MODE 1: C = out [M][256] + bias.
template<int MODE>
__global__ __launch_bounds__(256) void gemm_kernel(
    const unsigned short* __restrict__ A, const unsigned short* __restrict__ Bt,
    unsigned short* __restrict__ C, const float* __restrict__ bias, int M, int NB){
  __shared__ unsigned short As[2][128 * 64];
  __shared__ unsigned short Bs[2][128 * 64];
  const int r     = blockIdx.x / NB;
  const int nbase = (blockIdx.x % NB) * 128;
  const int mbase = blockIdx.y * 128;
  const int tid  = threadIdx.x;
  const int lane = tid & 63;
  const int wid  = tid >> 6;
  const int wm = (wid >> 1) * 64, wn = (wid & 1) * 64;
  const int lg = lane >> 4, lr = lane & 15;
  const unsigned short* Brel = Bt + (size_t)r * 65536;

  f32x4 acc[4][4];
  #pragma unroll
  for (int i = 0; i < 4; ++i)
    #pragma unroll
    for (int j = 0; j < 4; ++j) acc[i][j] = (f32x4)0.0f;

  auto stage = [&](int buf, int kt){
    #pragma unroll
    for (int q = 0; q < 4; ++q){
      int ci  = (q * 4 + wid) * 64 + lane;          // 0..1023
      int row = ci >> 3, p = ci & 7;
      int gch = p ^ (row & 7);                       // inverse-swizzled source
      int grow = mbase + row; if (grow >= M) grow = M - 1;
      const unsigned short* ga = A + (size_t)grow * 256 + kt * 64 + gch * 8;
      __builtin_amdgcn_global_load_lds((const __attribute__((address_space(1))) void*)ga,
          (__attribute__((address_space(3))) void*)(As[buf] + (size_t)(q * 4 + wid) * 512), 16, 0, 0);
      const unsigned short* gb = Brel + (size_t)(nbase + row) * 256 + kt * 64 + gch * 8;
      __builtin_amdgcn_global_load_lds((const __attribute__((address_space(1))) void*)gb,
          (__attribute__((address_space(3))) void*)(Bs[buf] + (size_t)(q * 4 + wid) * 512), 16, 0, 0);
    }
  };

  stage(0, 0);
  __syncthreads();

  for (int kt = 0; kt < 4; ++kt){
    const int cur = kt & 1;
    if (kt < 3) stage(cur ^ 1, kt + 1);              // prefetch overlaps compute
    #pragma unroll
    for (int kk = 0; kk < 2; ++kk){
      bf16x8 af[4], bg[4];
      #pragma unroll
      for (int mi = 0; mi < 4; ++mi){
        int row = wm + mi * 16 + lr;
        int pc = (lg + kk * 4) ^ (row & 7);
        af[mi] = *(const bf16x8*)&As[cur][row * 64 + pc * 8];
      }
      #pragma unroll
      for (int ni = 0; ni < 4; ++ni){
        int row = wn + ni * 16 + lr;
        int pc = (lg + kk * 4) ^ (row & 7);
        bg[ni] = *(const bf16x8*)&Bs[cur][row * 64 + pc * 8];
      }
      #pragma unroll
      for (int mi = 0; mi < 4; ++mi)
        #pragma unroll
        for (int ni = 0; ni < 4; ++ni)
          acc[mi][ni] = __builtin_amdgcn_mfma_f32_16x16x32_bf16(af[mi], bg[ni], acc[mi][ni], 0, 0, 0);
    }
    __syncthreads();
  }

  // epilogue: C/D layout col=lane&15, row=(lane>>4)*4+reg
  #pragma unroll
  for (int mi = 0; mi < 4; ++mi){
    #pragma unroll
    for (int j = 0; j < 4; ++j){
      int rowm = mbase + wm + mi * 16 + lg * 4 + j;
      if (rowm >= M) continue;
      #pragma unroll
      for (int ni = 0; ni < 4; ++ni){
        int col = nbase + wn + ni * 16 + lr;
        float v = acc[mi][ni][j];
        if (MODE == 0) C[((size_t)r * M + rowm) * H_ + col] = f2b(v);
        else           C[(size_t)rowm * H_ + col] = f2b(v + bias[col]);
      }
    }
  }
}

// ---------- aggregation: wave per node, 4 cols/lane, 4-edge ILP; et-clustered reads ----------
__global__ void agg3_kernel(const unsigned short* __restrict__ xt, const float* __restrict__ a,
                            const int* __restrict__ ps2, const int* __restrict__ es_src,
                            const int* __restrict__ es_et, unsigned short* __restrict__ hout, int n){
  int w = threadIdx.x >> 6, lane = threadIdx.x & 63;
  int node = blockIdx.x * 4 + w;
  if (node >= n) return;
  int kb = (node >> 5) * 1024 + (node & 31) * 32;
  int s = ps2[kb], e = ps2[kb + 32];
  float a0acc = 0.f, a1acc = 0.f, a2acc = 0.f, a3acc = 0.f;
  int j = s;
  for (; j + 4 <= e; j += 4){
    int sc0 = es_src[j],   et0 = es_et[j];
    int sc1 = es_src[j+1], et1 = es_et[j+1];
    int sc2 = es_src[j+2], et2 = es_et[j+2];
    int sc3 = es_src[j+3], et3 = es_et[j+3];
    float w0 = a[j], w1 = a[j+1], w2 = a[j+2], w3 = a[j+3];
    ushort4 v0 = ((const ushort4*)(xt + ((size_t)et0 * n + sc0) * 256))[lane];
    ushort4 v1 = ((const ushort4*)(xt + ((size_t)et1 * n + sc1) * 256))[lane];
    ushort4 v2 = ((const ushort4*)(xt + ((size_t)et2 * n + sc2) * 256))[lane];
    ushort4 v3 = ((const ushort4*)(xt + ((size_t)et3 * n + sc3) * 256))[lane];
    a0acc += w0*b2f(v0.x) + w1*b2f(v1.x) + w2*b2f(v2.x) + w3*b2f(v3.x);
    a1acc += w0*b2f(v0.y) + w1*b2f(v1.y) + w2*b2f(v2.y) + w3*b2f(v3.y);
    a2acc += w0*b2f(v0.z) + w1*b2f(v1.z) + w2*b2f(v2.z) + w3*b2f(v3.z);
    a3acc += w0*b2f(v0.w) + w1*b2f(v1.w) + w2*b2f(v2.w) + w3*b2f(v3.w);
  }
  for (; j < e; ++j){
    int sc = es_src[j], et = es_et[j];
    float wv = a[j];
    ushort4 v = ((const ushort4*)(xt + ((size_t)et * n + sc) * 256))[lane];
    a0acc = fmaf(wv, b2f(v.x), a0acc);
    a1acc = fmaf(wv, b2f(v.y), a1acc);
    a2acc = fmaf(wv, b2f(v.z), a2acc);
    a3acc = fmaf(wv, b2f(v.w), a3acc);
  }
  ushort4 o;
  o.x = f2b(fmaxf(a0acc, 0.f)); o.y = f2b(fmaxf(a1acc, 0.f));
  o.z = f2b(fmaxf(a2acc, 0.f)); o.w = f2b(fmaxf(a3acc, 0.f));
  ((ushort4*)(hout + (size_t)node * H_))[lane] = o;
}

// ---------- TransE scoring (wave per edge) ----------
__global__ void score_kernel(const unsigned short* __restrict__ hb, const unsigned short* __restrict__ relb,
                             const int* __restrict__ src_a, const int* __restrict__ dst_a,
                             const int* __restrict__ et_a, float* __restrict__ out, int E){
  int e = blockIdx.x * 4 + (threadIdx.x >> 6);
  int lane = threadIdx.x & 63;
  if (e >= E) return;
  int s = src_a[e], d = dst_a[e], r = et_a[e];
  ushort4 a4 = ((const ushort4*)(hb + (size_t)s * H_))[lane];
  ushort4 b4 = ((const ushort4*)(hb + (size_t)d * H_))[lane];
  ushort4 r4 = ((const ushort4*)(relb + (size_t)r * H_))[lane];
  float sum = fabsf(b2f(a4.x) + b2f(r4.x) - b2f(b4.x))
            + fabsf(b2f(a4.y) + b2f(r4.y) - b2f(b4.y))
            + fabsf(b2f(a4.z) + b2f(r4.z) - b2f(b4.z))
            + fabsf(b2f(a4.w) + b2f(r4.w) - b2f(b4.w));
  #pragma unroll
  for (int o = 32; o; o >>= 1) sum += __shfl_xor(sum, o);
  if (!lane) out[e] = GAMMA_ - sum;
}

extern "C" void kernel_launch(void* const* d_in, const int* in_sizes, int n_in,
                              void* d_out, int out_size, void* d_ws, size_t ws_size,
                              hipStream_t stream){
  const float* x         = (const float*)d_in[0];
  const int*   edge_idx  = (const int*)d_in[1];
  const int*   edge_type = (const int*)d_in[2];
  const float* W1        = (const float*)d_in[3];
  const float* q1        = (const float*)d_in[4];
  const float* k1        = (const float*)d_in[5];
  const float* W2        = (const float*)d_in[6];
  const float* q2        = (const float*)d_in[7];
  const float* k2        = (const float*)d_in[8];
  const float* lin_w     = (const float*)d_in[9];
  const float* lin_b     = (const float*)d_in[10];
  const float* rel_bert  = (const float*)d_in[11];
  const float* rel_lin_w = (const float*)d_in[12];
  const float* rel_lin_b = (const float*)d_in[13];
  float* score = (float*)d_out;

  const int Nn = in_sizes[0] / H_;   // 10000
  const int E  = in_sizes[1] / 2;    // 320000
  const int* src_a = edge_idx;
  const int* dst_a = edge_idx + E;
  const int NBLK  = (Nn + 31) / 32;  // 313
  const int NBINS = NBLK * 1024;

  // workspace carve-up (256B aligned)
  char* ws = (char*)d_ws;
  size_t cur_off = 0;
  auto carve = [&](size_t bytes)->char*{
    char* p = ws + cur_off;
    cur_off += (bytes + 255) & ~(size_t)255;
    return p;
  };
  unsigned short* xt   = (unsigned short*)carve((size_t)Nn * R_ * H_ * 2);
  unsigned short* xb   = (unsigned short*)carve((size_t)Nn * H_ * 2);
  unsigned short* h1   = (unsigned short*)carve((size_t)Nn * H_ * 2);
  unsigned short* h2   = (unsigned short*)carve((size_t)Nn * H_ * 2);
  unsigned short* outb = (unsigned short*)carve((size_t)Nn * H_ * 2);
  unsigned short* Wt1  = (unsigned short*)carve((size_t)R_ * 65536 * 2);
  unsigned short* Wt2  = (unsigned short*)carve((size_t)R_ * 65536 * 2);
  unsigned short* linT = (unsigned short*)carve(65536 * 2);
  unsigned short* relb = (unsigned short*)carve(R_ * H_ * 2);
  float* wqkT1 = (float*)carve(64 * H_ * 4);
  float* wqkT2 = (float*)carve(64 * H_ * 4);
  float* qdot  = (float*)carve((size_t)Nn * R_ * 4);
  float* kdot  = (float*)carve((size_t)Nn * R_ * 4);
  int* cnt2    = (int*)carve((size_t)NBINS * 4);
  int* cur2    = (int*)carve((size_t)NBINS * 4);
  int* tot     = (int*)carve((size_t)NBLK * 4);
  int* baseA   = (int*)carve((size_t)(NBLK + 1) * 4);
  int* ps2     = (int*)carve((size_t)(NBINS + 1) * 4);
  int* es_src  = (int*)carve((size_t)E * 4);
  int* es_et   = (int*)carve((size_t)E * 4);
  float* attn  = (float*)carve((size_t)E * 4);
  (void)ws_size; (void)n_in; (void)out_size;

  const int mt = (Nn + 127) / 128;

  // prep
  cvt_kernel<<<(Nn * H_ / 4 + 255) / 256, 256, 0, stream>>>(x, xb, Nn * H_ / 4);
  transw_kernel<<<dim3(8, 8, R_), dim3(32, 8), 0, stream>>>(W1, Wt1);
  transw_kernel<<<dim3(8, 8, R_), dim3(32, 8), 0, stream>>>(W2, Wt2);
  transw_kernel<<<dim3(8, 8, 1),  dim3(32, 8), 0, stream>>>(lin_w, linT);
  wqk_kernel<<<dim3(H_, R_), 64, 0, stream>>>(W1, q1, k1, wqkT1);
  wqk_kernel<<<dim3(H_, R_), 64, 0, stream>>>(W2, q2, k2, wqkT2);
  rel_kernel<<<R_, H_, 0, stream>>>(rel_bert, rel_lin_w, rel_lin_b, relb);

  // sorted-edge structure (shared by both layers): per-node contiguous, et-sorted
  hipMemsetAsync(cnt2, 0, (size_t)NBINS * 4, stream);
  hipMemsetAsync(cur2, 0, (size_t)NBINS * 4, stream);
  hist2_kernel<<<(E + 255) / 256, 256, 0, stream>>>(dst_a, edge_type, cnt2, E);
  totred_kernel<<<NBLK, 256, 0, stream>>>(cnt2, tot);
  scan_kernel<<<1, 1024, 0, stream>>>(tot, baseA, NBLK);
  ps2scan_kernel<<<NBLK, 256, 0, stream>>>(cnt2, baseA, ps2, NBLK, NBINS);
  scatter2_kernel<<<(E + 255) / 256, 256, 0, stream>>>(src_a, dst_a, edge_type, ps2, cur2, es_src, es_et, E);

  // ---- layer 1 ----
  gemm_kernel<0><<<dim3(R_ * 2, mt), 256, 0, stream>>>(xb, Wt1, xt, nullptr, Nn, 2);
  qdot_kernel<<<(Nn + 3) / 4, 256, 0, stream>>>(xb, wqkT1, qdot, kdot, Nn);
  attn2_kernel<<<(Nn + 3) / 4, 256, 0, stream>>>(qdot, kdot, ps2, es_src, attn, Nn);
  agg3_kernel<<<(Nn + 3) / 4, 256, 0, stream>>>(xt, attn, ps2, es_src, es_et, h1, Nn);

  // ---- layer 2 ----
  gemm_kernel<0><<<dim3(R_ * 2, mt), 256, 0, stream>>>(h1, Wt2, xt, nullptr, Nn, 2);
  qdot_kernel<<<(Nn + 3) / 4, 256, 0, stream>>>(h1, wqkT2, qdot, kdot, Nn);
  attn2_kernel<<<(Nn + 3) / 4, 256, 0, stream>>>(qdot, kdot, ps2, es_src, attn, Nn);
  agg3_kernel<<<(Nn + 3) / 4, 256, 0, stream>>>(xt, attn, ps2, es_src, es_et, h2, Nn);

  // ---- final linear + scoring ----
  gemm_kernel<1><<<dim3(2, mt), 256, 0, stream>>>(h2, linT, outb, lin_b, Nn, 2);
  score_kernel<<<(E + 3) / 4, 256, 0, stream>>>(outb, relb, src_a, dst_a, edge_type, score, E);
}

// Round 7
// 402.368 us; speedup vs baseline: 2.3096x; 1.0771x over previous
//
#include <hip/hip_runtime.h>
#include <hip/hip_bf16.h>
#include <stdint.h>

#define R_ 32
#define H_ 256
#define GAMMA_ 10.0f

typedef __attribute__((ext_vector_type(4))) float f32x4;
typedef __attribute__((ext_vector_type(8))) short bf16x8;

__device__ __forceinline__ unsigned short f2b(float f){
  union { float f; unsigned u; } v; v.f = f;
  unsigned r = v.u + 0x7FFFu + ((v.u >> 16) & 1u);
  return (unsigned short)(r >> 16);
}
__device__ __forceinline__ float b2f(unsigned short h){
  union { unsigned u; float f; } v; v.u = ((unsigned)h) << 16; return v.f;
}

// ================= prep mega-kernel: cvt | transw x3 | wqk x2 | rel | hist =================
__global__ __launch_bounds__(256) void prep_kernel(
    const float* __restrict__ x, unsigned short* __restrict__ xb, int n4,
    const float* __restrict__ W1, unsigned short* __restrict__ Wt1,
    const float* __restrict__ W2, unsigned short* __restrict__ Wt2,
    const float* __restrict__ lin_w, unsigned short* __restrict__ linT,
    const float* __restrict__ q1, const float* __restrict__ k1, float* __restrict__ wqkT1,
    const float* __restrict__ q2, const float* __restrict__ k2, float* __restrict__ wqkT2,
    const float* __restrict__ rb, const float* __restrict__ rw,
    const float* __restrict__ rbias, unsigned short* __restrict__ relb,
    const int* __restrict__ dst, const int* __restrict__ et, int* __restrict__ cnt2, int E,
    int nb0, int nb_tw, int nb_lin, int nb_wqk, int nb_rel, int nb_hist){
  __shared__ float tile[32][33];
  const int bx = blockIdx.x, t = threadIdx.x;
  const int b0 = nb0, b1 = b0 + nb_tw, b2 = b1 + nb_tw, b3 = b2 + nb_lin;
  const int b4 = b3 + nb_wqk, b5 = b4 + nb_wqk, b6 = b5 + nb_rel;

  if (bx < b0){                                   // ---- cvt fp32->bf16
    int i = bx * 256 + t;
    if (i < n4){
      float4 v = ((const float4*)x)[i];
      ushort4 o; o.x=f2b(v.x); o.y=f2b(v.y); o.z=f2b(v.z); o.w=f2b(v.w);
      ((ushort4*)xb)[i] = o;
    }
    return;
  }
  if (bx < b3){                                   // ---- transw (W1 | W2 | lin)
    const float* W; unsigned short* Wt; int local;
    if (bx < b1){ W = W1; Wt = Wt1; local = bx - b0; }
    else if (bx < b2){ W = W2; Wt = Wt2; local = bx - b1; }
    else { W = lin_w; Wt = linT; local = bx - b2; }
    int i0 = (local & 7) * 32, o0 = ((local >> 3) & 7) * 32, r = local >> 6;
    int tx = t & 31, ty = t >> 5;
    const float* Wr = W + (size_t)r * 65536;
    for (int rr = ty; rr < 32; rr += 8)
      tile[rr][tx] = Wr[(size_t)(i0 + rr) * 256 + o0 + tx];
    __syncthreads();
    unsigned short* outr = Wt + (size_t)r * 65536;
    for (int rr = ty; rr < 32; rr += 8)
      outr[(size_t)(o0 + rr) * 256 + i0 + tx] = f2b(tile[tx][rr]);
    return;
  }
  if (bx < b5){                                   // ---- wqk (W1 | W2)
    bool first = bx < b4;
    int local = bx - (first ? b3 : b4);
    int w = t >> 6, lane = t & 63;
    int p = local * 4 + w;                        // 0..8191
    int i = p & 255, r = p >> 8;
    const float* W  = first ? W1 : W2;
    const float* qv = first ? q1 : q2;
    const float* kv = first ? k1 : k2;
    const float* row = W + ((size_t)r * 256 + i) * 256;
    float sq = 0.f, sk = 0.f;
    #pragma unroll
    for (int q4 = 0; q4 < 4; ++q4){
      int o = lane + q4 * 64;
      float wv = row[o];
      sq += wv * qv[r * 256 + o];
      sk += wv * kv[r * 256 + o];
    }
    #pragma unroll
    for (int o = 32; o; o >>= 1){ sq += __shfl_xor(sq, o); sk += __shfl_xor(sk, o); }
    if (!lane){
      float* wq = first ? wqkT1 : wqkT2;
      wq[i * 64 + r] = sq; wq[i * 64 + 32 + r] = sk;
    }
    return;
  }
  if (bx < b6){                                   // ---- rel embedding
    int r = bx - b5, h = t;
    float acc = rbias[h];
    const float* br = rb + (size_t)r * 768;
    for (int i = 0; i < 768; ++i) acc += br[i] * rw[(size_t)i * 256 + h];
    relb[r * 256 + h] = f2b(fmaxf(acc, 0.f));
    return;
  }
  {                                               // ---- hist (sorted-edge bins)
    int e = (bx - b6) * 256 + t;
    if (e < E){
      int d = dst[e];
      atomicAdd(&cnt2[(d >> 5) * 1024 + (d & 31) * 32 + et[e]], 1);
    }
  }
}

// ================= CSR scan chain (unchanged from R6) =================
__global__ void totred_kernel(const int* __restrict__ cnt2, int* __restrict__ tot){
  __shared__ int red[256];
  int blk = blockIdx.x, t = threadIdx.x;
  int s = 0;
  #pragma unroll
  for (int q = 0; q < 4; ++q) s += cnt2[blk * 1024 + q * 256 + t];
  red[t] = s; __syncthreads();
  for (int o = 128; o; o >>= 1){ if (t < o) red[t] += red[t + o]; __syncthreads(); }
  if (!t) tot[blk] = red[0];
}
__global__ void scan_kernel(const int* __restrict__ deg, int* __restrict__ off, int n){
  __shared__ int carry;
  __shared__ int buf[1024];
  if (threadIdx.x == 0) carry = 0;
  __syncthreads();
  for (int base = 0; base < n; base += 1024){
    int i = base + threadIdx.x;
    int v = (i < n) ? deg[i] : 0;
    buf[threadIdx.x] = v; __syncthreads();
    for (int o = 1; o < 1024; o <<= 1){
      int t = (threadIdx.x >= o) ? buf[threadIdx.x - o] : 0;
      __syncthreads();
      buf[threadIdx.x] += t;
      __syncthreads();
    }
    if (i < n) off[i] = carry + buf[threadIdx.x] - v;   // exclusive
    __syncthreads();
    if (threadIdx.x == 1023) carry += buf[1023];
    __syncthreads();
  }
  if (threadIdx.x == 0) off[n] = carry;
}
__global__ __launch_bounds__(256) void ps2scan_kernel(const int* __restrict__ cnt2, const int* __restrict__ base,
                                                      int* __restrict__ ps2, int nblk, int nbins){
  __shared__ int sb[1024];
  int blk = blockIdx.x, t = threadIdx.x;
  int orig[4];
  #pragma unroll
  for (int q = 0; q < 4; ++q){ int i = q * 256 + t; orig[q] = cnt2[blk * 1024 + i]; sb[i] = orig[q]; }
  __syncthreads();
  for (int o = 1; o < 1024; o <<= 1){
    int v[4];
    #pragma unroll
    for (int q = 0; q < 4; ++q){ int i = q * 256 + t; v[q] = (i >= o) ? sb[i - o] : 0; }
    __syncthreads();
    #pragma unroll
    for (int q = 0; q < 4; ++q){ int i = q * 256 + t; sb[i] += v[q]; }
    __syncthreads();
  }
  int b = base[blk];
  #pragma unroll
  for (int q = 0; q < 4; ++q){ int i = q * 256 + t; ps2[blk * 1024 + i] = b + sb[i] - orig[q]; }
  if (blk == 0 && t == 0) ps2[nbins] = base[nblk];
}
__global__ void scatter2_kernel(const int* __restrict__ src, const int* __restrict__ dst,
                                const int* __restrict__ et, const int* __restrict__ ps2,
                                int* __restrict__ cur2, int* __restrict__ es_src,
                                int* __restrict__ es_et, int E){
  int e = blockIdx.x * 256 + threadIdx.x;
  if (e >= E) return;
  int d = dst[e], r = et[e];
  int key = (d >> 5) * 1024 + (d & 31) * 32 + r;
  int pos = ps2[key] + atomicAdd(&cur2[key], 1);
  es_src[pos] = src[e];
  es_et[pos]  = r;
}

// ================= GEMM (BK=32, 5 blocks/CU) + fused qdot tail blocks =================
// A:[M][256] bf16. Bt:[R][256n][256k] bf16. MODE0: C=xt[r][M][256]; MODE1: C=[M][256]+bias.
template<int MODE>
__global__ __launch_bounds__(256) void gemmq_kernel(
    const unsigned short* __restrict__ A, const unsigned short* __restrict__ Bt,
    unsigned short* __restrict__ C, const float* __restrict__ bias, int M, int g_gemm,
    const float* __restrict__ wqkT, float* __restrict__ qdot, float* __restrict__ kdot){
  __shared__ unsigned short As[2][128 * 32];
  __shared__ unsigned short Bs[2][128 * 32];
  const int tid = threadIdx.x, lane = tid & 63, wid = tid >> 6;
  const int bx = blockIdx.x;

  if (MODE == 0 && bx >= g_gemm){
    // ---- qdot tail: wave per node, lane = output, coalesced wqkT
    int node = (bx - g_gemm) * 4 + wid;
    if (node >= M) return;
    float* xr = ((float*)As) + wid * 256;
    ushort4 v = ((const ushort4*)(A + (size_t)node * 256))[lane];
    xr[lane * 4 + 0] = b2f(v.x);
    xr[lane * 4 + 1] = b2f(v.y);
    xr[lane * 4 + 2] = b2f(v.z);
    xr[lane * 4 + 3] = b2f(v.w);
    float acc = 0.f;
    #pragma unroll 8
    for (int kk = 0; kk < 256; ++kk)
      acc = fmaf(xr[kk], wqkT[kk * 64 + lane], acc);
    if (lane < 32) qdot[node * 32 + lane] = acc;
    else           kdot[node * 32 + lane - 32] = acc;
    return;
  }

  const int x = (MODE == 0) ? (bx & 63) : (bx & 1);
  const int y = (MODE == 0) ? (bx >> 6) : (bx >> 1);
  const int r = (MODE == 0) ? (x >> 1) : 0;
  const int nbase = (x & 1) * 128;
  const int mbase = y * 128;
  const int wm = (wid >> 1) * 64, wn = (wid & 1) * 64;
  const int lg = lane >> 4, lr = lane & 15;
  const unsigned short* Brel = Bt + (size_t)r * 65536;

  f32x4 acc[4][4];
  #pragma unroll
  for (int i = 0; i < 4; ++i)
    #pragma unroll
    for (int j = 0; j < 4; ++j) acc[i][j] = (f32x4)0.0f;

  auto stage = [&](int buf, int kt){
    #pragma unroll
    for (int q = 0; q < 2; ++q){
      int ci = q * 256 + tid;                      // 0..511
      int row = ci >> 2, p = ci & 3;
      int gch = p ^ ((row >> 1) & 3);              // inverse-swizzled source chunk
      int grow = mbase + row; if (grow >= M) grow = M - 1;
      const unsigned short* ga = A + (size_t)grow * 256 + kt * 32 + gch * 8;
      __builtin_amdgcn_global_load_lds((const __attribute__((address_space(1))) void*)ga,
          (__attribute__((address_space(3))) void*)(As[buf] + (size_t)ci * 8), 16, 0, 0);
      const unsigned short* gb = Brel + (size_t)(nbase + row) * 256 + kt * 32 + gch * 8;
      __builtin_amdgcn_global_load_lds((const __attribute__((address_space(1))) void*)gb,
          (__attribute__((address_space(3))) void*)(Bs[buf] + (size_t)ci * 8), 16, 0, 0);
    }
  };

  stage(0, 0);
  __syncthreads();

  for (int kt = 0; kt < 8; ++kt){
    const int cur = kt & 1;
    if (kt < 7) stage(cur ^ 1, kt + 1);            // prefetch overlaps compute
    bf16x8 af[4], bg[4];
    #pragma unroll
    for (int mi = 0; mi < 4; ++mi){
      int row = wm + mi * 16 + lr;
      int sl = lg ^ ((row >> 1) & 3);
      af[mi] = *(const bf16x8*)&As[cur][row * 32 + sl * 8];
    }
    #pragma unroll
    for (int ni = 0; ni < 4; ++ni){
      int row = wn + ni * 16 + lr;
      int sl = lg ^ ((row >> 1) & 3);
      bg[ni] = *(const bf16x8*)&Bs[cur][row * 32 + sl * 8];
    }
    #pragma unroll
    for (int mi = 0; mi < 4; ++mi)
      #pragma unroll
      for (int ni = 0; ni < 4; ++ni)
        acc[mi][ni] = __builtin_amdgcn_mfma_f32_16x16x32_bf16(af[mi], bg[ni], acc[mi][ni], 0, 0, 0);
    __syncthreads();
  }

  // epilogue: C/D layout col=lane&15, row=(lane>>4)*4+reg
  #pragma unroll
  for (int mi = 0; mi < 4; ++mi){
    #pragma unroll
    for (int j = 0; j < 4; ++j){
      int rowm = mbase + wm + mi * 16 + lg * 4 + j;
      if (rowm >= M) continue;
      #pragma unroll
      for (int ni = 0; ni < 4; ++ni){
        int col = nbase + wn + ni * 16 + lr;
        float v = acc[mi][ni][j];
        if (MODE == 0) C[((size_t)r * M + rowm) * H_ + col] = f2b(v);
        else           C[(size_t)rowm * H_ + col] = f2b(v + bias[col]);
      }
    }
  }
}

// ================= fused softmax + aggregation: wave per node =================
__global__ void attn_agg_kernel(const unsigned short* __restrict__ xt, const float* __restrict__ qdot,
                                const float* __restrict__ kdot, const int* __restrict__ ps2,
                                const int* __restrict__ es_src, const int* __restrict__ es_et,
                                float* __restrict__ a, unsigned short* __restrict__ hout, int n){
  int w = threadIdx.x >> 6, lane = threadIdx.x & 63;
  int node = blockIdx.x * 4 + w;
  if (node >= n) return;
  int kb = (node >> 5) * 1024 + (node & 31) * 32;
  // ---- phase A: softmax stats; lane r owns the node's (et=r) run; store raw exp
  int s = 0, e = 0;
  float qd = 0.f;
  if (lane < 32){
    s = ps2[kb + lane]; e = ps2[kb + lane + 1];
    qd = qdot[node * 32 + lane];
  }
  float m = -1e30f;
  for (int j = s; j < e; ++j){
    float z = qd + kdot[es_src[j] * 32 + lane];
    z = (z > 0.f) ? z : 0.2f * z;          // leaky_relu 0.2
    a[j] = z;
    m = fmaxf(m, z);
  }
  #pragma unroll
  for (int o = 32; o; o >>= 1) m = fmaxf(m, __shfl_xor(m, o));
  float sum = 0.f;
  for (int j = s; j < e; ++j){
    float ez = __expf(a[j] - m);
    a[j] = ez; sum += ez;
  }
  #pragma unroll
  for (int o = 32; o; o >>= 1) sum += __shfl_xor(sum, o);
  float inv = 1.0f / (sum + 1e-16f);
  // ---- phase B: aggregate 4 cols/lane over the node's full edge range; scale by inv at end
  int s0 = ps2[kb], s1 = ps2[kb + 32];
  float a0 = 0.f, a1 = 0.f, a2 = 0.f, a3 = 0.f;
  int j = s0;
  for (; j + 4 <= s1; j += 4){
    int sc0 = es_src[j],   et0 = es_et[j];
    int sc1 = es_src[j+1], et1 = es_et[j+1];
    int sc2 = es_src[j+2], et2 = es_et[j+2];
    int sc3 = es_src[j+3], et3 = es_et[j+3];
    float w0 = a[j], w1 = a[j+1], w2 = a[j+2], w3 = a[j+3];
    ushort4 v0 = ((const ushort4*)(xt + ((size_t)et0 * n + sc0) * 256))[lane];
    ushort4 v1 = ((const ushort4*)(xt + ((size_t)et1 * n + sc1) * 256))[lane];
    ushort4 v2 = ((const ushort4*)(xt + ((size_t)et2 * n + sc2) * 256))[lane];
    ushort4 v3 = ((const ushort4*)(xt + ((size_t)et3 * n + sc3) * 256))[lane];
    a0 += w0*b2f(v0.x) + w1*b2f(v1.x) + w2*b2f(v2.x) + w3*b2f(v3.x);
    a1 += w0*b2f(v0.y) + w1*b2f(v1.y) + w2*b2f(v2.y) + w3*b2f(v3.y);
    a2 += w0*b2f(v0.z) + w1*b2f(v1.z) + w2*b2f(v2.z) + w3*b2f(v3.z);
    a3 += w0*b2f(v0.w) + w1*b2f(v1.w) + w2*b2f(v2.w) + w3*b2f(v3.w);
  }
  for (; j < s1; ++j){
    int sc = es_src[j], et = es_et[j];
    float wv = a[j];
    ushort4 v = ((const ushort4*)(xt + ((size_t)et * n + sc) * 256))[lane];
    a0 = fmaf(wv, b2f(v.x), a0);
    a1 = fmaf(wv, b2f(v.y), a1);
    a2 = fmaf(wv, b2f(v.z), a2);
    a3 = fmaf(wv, b2f(v.w), a3);
  }
  ushort4 o;
  o.x = f2b(fmaxf(a0 * inv, 0.f)); o.y = f2b(fmaxf(a1 * inv, 0.f));
  o.z = f2b(fmaxf(a2 * inv, 0.f)); o.w = f2b(fmaxf(a3 * inv, 0.f));
  ((ushort4*)(hout + (size_t)node * H_))[lane] = o;
}

// ================= TransE scoring (wave per edge) =================
__global__ void score_kernel(const unsigned short* __restrict__ hb, const unsigned short* __restrict__ relb,
                             const int* __restrict__ src_a, const int* __restrict__ dst_a,
                             const int* __restrict__ et_a, float* __restrict__ out, int E){
  int e = blockIdx.x * 4 + (threadIdx.x >> 6);
  int lane = threadIdx.x & 63;
  if (e >= E) return;
  int s = src_a[e], d = dst_a[e], r = et_a[e];
  ushort4 a4 = ((const ushort4*)(hb + (size_t)s * H_))[lane];
  ushort4 b4 = ((const ushort4*)(hb + (size_t)d * H_))[lane];
  ushort4 r4 = ((const ushort4*)(relb + (size_t)r * H_))[lane];
  float sum = fabsf(b2f(a4.x) + b2f(r4.x) - b2f(b4.x))
            + fabsf(b2f(a4.y) + b2f(r4.y) - b2f(b4.y))
            + fabsf(b2f(a4.z) + b2f(r4.z) - b2f(b4.z))
            + fabsf(b2f(a4.w) + b2f(r4.w) - b2f(b4.w));
  #pragma unroll
  for (int o = 32; o; o >>= 1) sum += __shfl_xor(sum, o);
  if (!lane) out[e] = GAMMA_ - sum;
}

extern "C" void kernel_launch(void* const* d_in, const int* in_sizes, int n_in,
                              void* d_out, int out_size, void* d_ws, size_t ws_size,
                              hipStream_t stream){
  const float* x         = (const float*)d_in[0];
  const int*   edge_idx  = (const int*)d_in[1];
  const int*   edge_type = (const int*)d_in[2];
  const float* W1        = (const float*)d_in[3];
  const float* q1        = (const float*)d_in[4];
  const float* k1        = (const float*)d_in[5];
  const float* W2        = (const float*)d_in[6];
  const float* q2        = (const float*)d_in[7];
  const float* k2        = (const float*)d_in[8];
  const float* lin_w     = (const float*)d_in[9];
  const float* lin_b     = (const float*)d_in[10];
  const float* rel_bert  = (const float*)d_in[11];
  const float* rel_lin_w = (const float*)d_in[12];
  const float* rel_lin_b = (const float*)d_in[13];
  float* score = (float*)d_out;

  const int Nn = in_sizes[0] / H_;   // 10000
  const int E  = in_sizes[1] / 2;    // 320000
  const int* src_a = edge_idx;
  const int* dst_a = edge_idx + E;
  const int NBLK  = (Nn + 31) / 32;  // 313
  const int NBINS = NBLK * 1024;

  // workspace carve-up (256B aligned)
  char* ws = (char*)d_ws;
  size_t cur_off = 0;
  auto carve = [&](size_t bytes)->char*{
    char* p = ws + cur_off;
    cur_off += (bytes + 255) & ~(size_t)255;
    return p;
  };
  unsigned short* xt   = (unsigned short*)carve((size_t)Nn * R_ * H_ * 2);
  unsigned short* xb   = (unsigned short*)carve((size_t)Nn * H_ * 2);
  unsigned short* h1   = (unsigned short*)carve((size_t)Nn * H_ * 2);
  unsigned short* h2   = (unsigned short*)carve((size_t)Nn * H_ * 2);
  unsigned short* outb = (unsigned short*)carve((size_t)Nn * H_ * 2);
  unsigned short* Wt1  = (unsigned short*)carve((size_t)R_ * 65536 * 2);
  unsigned short* Wt2  = (unsigned short*)carve((size_t)R_ * 65536 * 2);
  unsigned short* linT = (unsigned short*)carve(65536 * 2);
  unsigned short* relb = (unsigned short*)carve(R_ * H_ * 2);
  float* wqkT1 = (float*)carve(64 * H_ * 4);
  float* wqkT2 = (float*)carve(64 * H_ * 4);
  float* qdot  = (float*)carve((size_t)Nn * R_ * 4);
  float* kdot  = (float*)carve((size_t)Nn * R_ * 4);
  int* cnt2    = (int*)carve((size_t)NBINS * 4);
  int* cur2    = (int*)carve((size_t)NBINS * 4);
  int* tot     = (int*)carve((size_t)NBLK * 4);
  int* baseA   = (int*)carve((size_t)(NBLK + 1) * 4);
  int* ps2     = (int*)carve((size_t)(NBINS + 1) * 4);
  int* es_src  = (int*)carve((size_t)E * 4);
  int* es_et   = (int*)carve((size_t)E * 4);
  float* attn  = (float*)carve((size_t)E * 4);
  (void)ws_size; (void)n_in; (void)out_size;

  const int mt = (Nn + 127) / 128;         // 79
  const int g_gemm = 64 * mt;              // 5056 gemm blocks (MODE 0)
  const int nqd = (Nn + 3) / 4;            // 2500 qdot/attn_agg blocks

  // prep block ranges
  const int n4 = Nn * H_ / 4;
  const int nb0 = (n4 + 255) / 256, nb_tw = 2048, nb_lin = 64, nb_wqk = 2048, nb_rel = 32;
  const int nb_hist = (E + 255) / 256;
  const int nprep = nb0 + 2 * nb_tw + nb_lin + 2 * nb_wqk + nb_rel + nb_hist;

  hipMemsetAsync(cnt2, 0, (size_t)NBINS * 4, stream);
  hipMemsetAsync(cur2, 0, (size_t)NBINS * 4, stream);

  prep_kernel<<<nprep, 256, 0, stream>>>(
      x, xb, n4, W1, Wt1, W2, Wt2, lin_w, linT,
      q1, k1, wqkT1, q2, k2, wqkT2,
      rel_bert, rel_lin_w, rel_lin_b, relb,
      dst_a, edge_type, cnt2, E,
      nb0, nb_tw, nb_lin, nb_wqk, nb_rel, nb_hist);

  totred_kernel<<<NBLK, 256, 0, stream>>>(cnt2, tot);
  scan_kernel<<<1, 1024, 0, stream>>>(tot, baseA, NBLK);
  ps2scan_kernel<<<NBLK, 256, 0, stream>>>(cnt2, baseA, ps2, NBLK, NBINS);
  scatter2_kernel<<<(E + 255) / 256, 256, 0, stream>>>(src_a, dst_a, edge_type, ps2, cur2, es_src, es_et, E);

  // ---- layer 1 ----
  gemmq_kernel<0><<<g_gemm + nqd, 256, 0, stream>>>(xb, Wt1, xt, nullptr, Nn, g_gemm, wqkT1, qdot, kdot);
  attn_agg_kernel<<<nqd, 256, 0, stream>>>(xt, qdot, kdot, ps2, es_src, es_et, attn, h1, Nn);

  // ---- layer 2 ----
  gemmq_kernel<0><<<g_gemm + nqd, 256, 0, stream>>>(h1, Wt2, xt, nullptr, Nn, g_gemm, wqkT2, qdot, kdot);
  attn_agg_kernel<<<nqd, 256, 0, stream>>>(xt, qdot, kdot, ps2, es_src, es_et, attn, h2, Nn);

  // ---- final linear + scoring ----
  gemmq_kernel<1><<<2 * mt, 256, 0, stream>>>(h2, linT, outb, lin_b, Nn, 2 * mt, nullptr, nullptr, nullptr);
  score_kernel<<<(E + 3) / 4, 256, 0, stream>>>(outb, relb, src_a, dst_a, edge_type, score, E);
}

// Round 8
// 397.793 us; speedup vs baseline: 2.3361x; 1.0115x over previous
//
#include <hip/hip_runtime.h>
#include <hip/hip_bf16.h>
#include <stdint.h>

#define R_ 32
#define H_ 256
#define GAMMA_ 10.0f

typedef __attribute__((ext_vector_type(4))) float f32x4;
typedef __attribute__((ext_vector_type(8))) short bf16x8;

__device__ __forceinline__ unsigned short f2b(float f){
  union { float f; unsigned u; } v; v.f = f;
  unsigned r = v.u + 0x7FFFu + ((v.u >> 16) & 1u);
  return (unsigned short)(r >> 16);
}
__device__ __forceinline__ float b2f(unsigned short h){
  union { unsigned u; float f; } v; v.u = ((unsigned)h) << 16; return v.f;
}

// ================= prep mega-kernel: cvt | transw x3 | wqk x2 | rel | hist =================
__global__ __launch_bounds__(256) void prep_kernel(
    const float* __restrict__ x, unsigned short* __restrict__ xb, int n4,
    const float* __restrict__ W1, unsigned short* __restrict__ Wt1,
    const float* __restrict__ W2, unsigned short* __restrict__ Wt2,
    const float* __restrict__ lin_w, unsigned short* __restrict__ linT,
    const float* __restrict__ q1, const float* __restrict__ k1, float* __restrict__ wqkT1,
    const float* __restrict__ q2, const float* __restrict__ k2, float* __restrict__ wqkT2,
    const float* __restrict__ rb, const float* __restrict__ rw,
    const float* __restrict__ rbias, unsigned short* __restrict__ relb,
    const int* __restrict__ dst, const int* __restrict__ et, int* __restrict__ cnt2, int E,
    int nb0, int nb_tw, int nb_lin, int nb_wqk, int nb_rel, int nb_hist){
  __shared__ float tile[32][33];
  const int bx = blockIdx.x, t = threadIdx.x;
  const int b0 = nb0, b1 = b0 + nb_tw, b2 = b1 + nb_tw, b3 = b2 + nb_lin;
  const int b4 = b3 + nb_wqk, b5 = b4 + nb_wqk, b6 = b5 + nb_rel;

  if (bx < b0){                                   // ---- cvt fp32->bf16
    int i = bx * 256 + t;
    if (i < n4){
      float4 v = ((const float4*)x)[i];
      ushort4 o; o.x=f2b(v.x); o.y=f2b(v.y); o.z=f2b(v.z); o.w=f2b(v.w);
      ((ushort4*)xb)[i] = o;
    }
    return;
  }
  if (bx < b3){                                   // ---- transw (W1 | W2 | lin)
    const float* W; unsigned short* Wt; int local;
    if (bx < b1){ W = W1; Wt = Wt1; local = bx - b0; }
    else if (bx < b2){ W = W2; Wt = Wt2; local = bx - b1; }
    else { W = lin_w; Wt = linT; local = bx - b2; }
    int i0 = (local & 7) * 32, o0 = ((local >> 3) & 7) * 32, r = local >> 6;
    int tx = t & 31, ty = t >> 5;
    const float* Wr = W + (size_t)r * 65536;
    for (int rr = ty; rr < 32; rr += 8)
      tile[rr][tx] = Wr[(size_t)(i0 + rr) * 256 + o0 + tx];
    __syncthreads();
    unsigned short* outr = Wt + (size_t)r * 65536;
    for (int rr = ty; rr < 32; rr += 8)
      outr[(size_t)(o0 + rr) * 256 + i0 + tx] = f2b(tile[tx][rr]);
    return;
  }
  if (bx < b5){                                   // ---- wqk (W1 | W2)
    bool first = bx < b4;
    int local = bx - (first ? b3 : b4);
    int w = t >> 6, lane = t & 63;
    int p = local * 4 + w;                        // 0..8191
    int i = p & 255, r = p >> 8;
    const float* W  = first ? W1 : W2;
    const float* qv = first ? q1 : q2;
    const float* kv = first ? k1 : k2;
    const float* row = W + ((size_t)r * 256 + i) * 256;
    float sq = 0.f, sk = 0.f;
    #pragma unroll
    for (int q4 = 0; q4 < 4; ++q4){
      int o = lane + q4 * 64;
      float wv = row[o];
      sq += wv * qv[r * 256 + o];
      sk += wv * kv[r * 256 + o];
    }
    #pragma unroll
    for (int o = 32; o; o >>= 1){ sq += __shfl_xor(sq, o); sk += __shfl_xor(sk, o); }
    if (!lane){
      float* wq = first ? wqkT1 : wqkT2;
      wq[i * 64 + r] = sq; wq[i * 64 + 32 + r] = sk;
    }
    return;
  }
  if (bx < b6){                                   // ---- rel embedding
    int r = bx - b5, h = t;
    float acc = rbias[h];
    const float* br = rb + (size_t)r * 768;
    for (int i = 0; i < 768; ++i) acc += br[i] * rw[(size_t)i * 256 + h];
    relb[r * 256 + h] = f2b(fmaxf(acc, 0.f));
    return;
  }
  {                                               // ---- hist (sorted-edge bins)
    int e = (bx - b6) * 256 + t;
    if (e < E){
      int d = dst[e];
      atomicAdd(&cnt2[(d >> 5) * 1024 + (d & 31) * 32 + et[e]], 1);
    }
  }
}

// ================= CSR scan chain =================
__global__ void totred_kernel(const int* __restrict__ cnt2, int* __restrict__ tot){
  __shared__ int red[256];
  int blk = blockIdx.x, t = threadIdx.x;
  int s = 0;
  #pragma unroll
  for (int q = 0; q < 4; ++q) s += cnt2[blk * 1024 + q * 256 + t];
  red[t] = s; __syncthreads();
  for (int o = 128; o; o >>= 1){ if (t < o) red[t] += red[t + o]; __syncthreads(); }
  if (!t) tot[blk] = red[0];
}
__global__ void scan_kernel(const int* __restrict__ deg, int* __restrict__ off, int n){
  __shared__ int carry;
  __shared__ int buf[1024];
  if (threadIdx.x == 0) carry = 0;
  __syncthreads();
  for (int base = 0; base < n; base += 1024){
    int i = base + threadIdx.x;
    int v = (i < n) ? deg[i] : 0;
    buf[threadIdx.x] = v; __syncthreads();
    for (int o = 1; o < 1024; o <<= 1){
      int t = (threadIdx.x >= o) ? buf[threadIdx.x - o] : 0;
      __syncthreads();
      buf[threadIdx.x] += t;
      __syncthreads();
    }
    if (i < n) off[i] = carry + buf[threadIdx.x] - v;   // exclusive
    __syncthreads();
    if (threadIdx.x == 1023) carry += buf[1023];
    __syncthreads();
  }
  if (threadIdx.x == 0) off[n] = carry;
}
__global__ __launch_bounds__(256) void ps2scan_kernel(const int* __restrict__ cnt2, const int* __restrict__ base,
                                                      int* __restrict__ ps2, int nblk, int nbins){
  __shared__ int sb[1024];
  int blk = blockIdx.x, t = threadIdx.x;
  int orig[4];
  #pragma unroll
  for (int q = 0; q < 4; ++q){ int i = q * 256 + t; orig[q] = cnt2[blk * 1024 + i]; sb[i] = orig[q]; }
  __syncthreads();
  for (int o = 1; o < 1024; o <<= 1){
    int v[4];
    #pragma unroll
    for (int q = 0; q < 4; ++q){ int i = q * 256 + t; v[q] = (i >= o) ? sb[i - o] : 0; }
    __syncthreads();
    #pragma unroll
    for (int q = 0; q < 4; ++q){ int i = q * 256 + t; sb[i] += v[q]; }
    __syncthreads();
  }
  int b = base[blk];
  #pragma unroll
  for (int q = 0; q < 4; ++q){ int i = q * 256 + t; ps2[blk * 1024 + i] = b + sb[i] - orig[q]; }
  if (blk == 0 && t == 0) ps2[nbins] = base[nblk];
}
__global__ void scatter2_kernel(const int* __restrict__ src, const int* __restrict__ dst,
                                const int* __restrict__ et, const int* __restrict__ ps2,
                                int* __restrict__ cur2, int* __restrict__ es_src,
                                int* __restrict__ es_et, int E){
  int e = blockIdx.x * 256 + threadIdx.x;
  if (e >= E) return;
  int d = dst[e], r = et[e];
  int key = (d >> 5) * 1024 + (d & 31) * 32 + r;
  int pos = ps2[key] + atomicAdd(&cur2[key], 1);
  es_src[pos] = src[e];
  es_et[pos]  = r;
}

// ================= GEMM (BK=64, R6-proven loop) + LDS-coalesced epilogue + qdot tail =================
// A:[M][256] bf16. Bt:[R][256n][256k] bf16. MODE0: C=xt[r][M][256]; MODE1: C=[M][256]+bias.
template<int MODE>
__global__ __launch_bounds__(256) void gemmq_kernel(
    const unsigned short* __restrict__ A, const unsigned short* __restrict__ Bt,
    unsigned short* __restrict__ C, const float* __restrict__ bias, int M, int g_gemm,
    const float* __restrict__ wqkT, float* __restrict__ qdot, float* __restrict__ kdot){
  __shared__ unsigned short As[2][128 * 64];
  __shared__ unsigned short Bs[2][128 * 64];
  const int tid = threadIdx.x, lane = tid & 63, wid = tid >> 6;
  const int bx = blockIdx.x;

  if (MODE == 0 && bx >= g_gemm){
    // ---- qdot tail: wave per node, lane = output, coalesced wqkT
    int node = (bx - g_gemm) * 4 + wid;
    if (node >= M) return;
    float* xr = ((float*)As) + wid * 256;
    ushort4 v = ((const ushort4*)(A + (size_t)node * 256))[lane];
    xr[lane * 4 + 0] = b2f(v.x);
    xr[lane * 4 + 1] = b2f(v.y);
    xr[lane * 4 + 2] = b2f(v.z);
    xr[lane * 4 + 3] = b2f(v.w);
    float acc = 0.f;
    #pragma unroll 8
    for (int kk = 0; kk < 256; ++kk)
      acc = fmaf(xr[kk], wqkT[kk * 64 + lane], acc);
    if (lane < 32) qdot[node * 32 + lane] = acc;
    else           kdot[node * 32 + lane - 32] = acc;
    return;
  }

  const int x = (MODE == 0) ? (bx & 63) : (bx & 1);
  const int y = (MODE == 0) ? (bx >> 6) : (bx >> 1);
  const int r = (MODE == 0) ? (x >> 1) : 0;
  const int nbase = (x & 1) * 128;
  const int mbase = y * 128;
  const int wm = (wid >> 1) * 64, wn = (wid & 1) * 64;
  const int lg = lane >> 4, lr = lane & 15;
  const unsigned short* Brel = Bt + (size_t)r * 65536;

  f32x4 acc[4][4];
  #pragma unroll
  for (int i = 0; i < 4; ++i)
    #pragma unroll
    for (int j = 0; j < 4; ++j) acc[i][j] = (f32x4)0.0f;

  auto stage = [&](int buf, int kt){
    #pragma unroll
    for (int q = 0; q < 4; ++q){
      int ci  = (q * 4 + wid) * 64 + lane;          // 0..1023
      int row = ci >> 3, p = ci & 7;
      int gch = p ^ (row & 7);                       // inverse-swizzled source
      int grow = mbase + row; if (grow >= M) grow = M - 1;
      const unsigned short* ga = A + (size_t)grow * 256 + kt * 64 + gch * 8;
      __builtin_amdgcn_global_load_lds((const __attribute__((address_space(1))) void*)ga,
          (__attribute__((address_space(3))) void*)(As[buf] + (size_t)(q * 4 + wid) * 512), 16, 0, 0);
      const unsigned short* gb = Brel + (size_t)(nbase + row) * 256 + kt * 64 + gch * 8;
      __builtin_amdgcn_global_load_lds((const __attribute__((address_space(1))) void*)gb,
          (__attribute__((address_space(3))) void*)(Bs[buf] + (size_t)(q * 4 + wid) * 512), 16, 0, 0);
    }
  };

  stage(0, 0);
  __syncthreads();

  for (int kt = 0; kt < 4; ++kt){
    const int cur = kt & 1;
    if (kt < 3) stage(cur ^ 1, kt + 1);              // prefetch overlaps compute
    #pragma unroll
    for (int kk = 0; kk < 2; ++kk){
      bf16x8 af[4], bg[4];
      #pragma unroll
      for (int mi = 0; mi < 4; ++mi){
        int row = wm + mi * 16 + lr;
        int pc = (lg + kk * 4) ^ (row & 7);
        af[mi] = *(const bf16x8*)&As[cur][row * 64 + pc * 8];
      }
      #pragma unroll
      for (int ni = 0; ni < 4; ++ni){
        int row = wn + ni * 16 + lr;
        int pc = (lg + kk * 4) ^ (row & 7);
        bg[ni] = *(const bf16x8*)&Bs[cur][row * 64 + pc * 8];
      }
      #pragma unroll
      for (int mi = 0; mi < 4; ++mi)
        #pragma unroll
        for (int ni = 0; ni < 4; ++ni)
          acc[mi][ni] = __builtin_amdgcn_mfma_f32_16x16x32_bf16(af[mi], bg[ni], acc[mi][ni], 0, 0, 0);
    }
    __syncthreads();
  }

  // ---- epilogue: acc -> LDS bf16 [128][136] (pad: conflict-free) -> coalesced 16B writes
  unsigned short* c_lds = (unsigned short*)As;       // 34.8 KB overlay, compute is done
  #pragma unroll
  for (int mi = 0; mi < 4; ++mi){
    #pragma unroll
    for (int j = 0; j < 4; ++j){
      int row = wm + mi * 16 + lg * 4 + j;
      #pragma unroll
      for (int ni = 0; ni < 4; ++ni){
        int col = wn + ni * 16 + lr;
        float v = acc[mi][ni][j];
        if (MODE == 1) v += bias[nbase + col];
        c_lds[row * 136 + col] = f2b(v);
      }
    }
  }
  __syncthreads();
  #pragma unroll
  for (int it = 0; it < 8; ++it){
    int c = it * 256 + tid;                          // 0..2047
    int row = c >> 4, ch = c & 15;
    int rowm = mbase + row;
    if (rowm < M){
      bf16x8 v = *(const bf16x8*)&c_lds[row * 136 + ch * 8];
      if (MODE == 0) *(bf16x8*)&C[((size_t)r * M + rowm) * H_ + nbase + ch * 8] = v;
      else           *(bf16x8*)&C[(size_t)rowm * H_ + nbase + ch * 8] = v;
    }
  }
}

// ================= fused softmax + aggregation: wave per node =================
__global__ void attn_agg_kernel(const unsigned short* __restrict__ xt, const float* __restrict__ qdot,
                                const float* __restrict__ kdot, const int* __restrict__ ps2,
                                const int* __restrict__ es_src, const int* __restrict__ es_et,
                                float* __restrict__ a, unsigned short* __restrict__ hout, int n){
  int w = threadIdx.x >> 6, lane = threadIdx.x & 63;
  int node = blockIdx.x * 4 + w;
  if (node >= n) return;
  int kb = (node >> 5) * 1024 + (node & 31) * 32;
  // ---- phase A: softmax stats; lane r owns the node's (et=r) run; store raw exp
  int s = 0, e = 0;
  float qd = 0.f;
  if (lane < 32){
    s = ps2[kb + lane]; e = ps2[kb + lane + 1];
    qd = qdot[node * 32 + lane];
  }
  float m = -1e30f;
  for (int j = s; j < e; ++j){
    float z = qd + kdot[es_src[j] * 32 + lane];
    z = (z > 0.f) ? z : 0.2f * z;          // leaky_relu 0.2
    a[j] = z;
    m = fmaxf(m, z);
  }
  #pragma unroll
  for (int o = 32; o; o >>= 1) m = fmaxf(m, __shfl_xor(m, o));
  float sum = 0.f;
  for (int j = s; j < e; ++j){
    float ez = __expf(a[j] - m);
    a[j] = ez; sum += ez;
  }
  #pragma unroll
  for (int o = 32; o; o >>= 1) sum += __shfl_xor(sum, o);
  float inv = 1.0f / (sum + 1e-16f);
  // ---- phase B: aggregate 4 cols/lane over the node's full edge range; scale at end
  int s0 = ps2[kb], s1 = ps2[kb + 32];
  float a0 = 0.f, a1 = 0.f, a2 = 0.f, a3 = 0.f;
  int j = s0;
  for (; j + 4 <= s1; j += 4){
    int sc0 = es_src[j],   et0 = es_et[j];
    int sc1 = es_src[j+1], et1 = es_et[j+1];
    int sc2 = es_src[j+2], et2 = es_et[j+2];
    int sc3 = es_src[j+3], et3 = es_et[j+3];
    float w0 = a[j], w1 = a[j+1], w2 = a[j+2], w3 = a[j+3];
    ushort4 v0 = ((const ushort4*)(xt + ((size_t)et0 * n + sc0) * 256))[lane];
    ushort4 v1 = ((const ushort4*)(xt + ((size_t)et1 * n + sc1) * 256))[lane];
    ushort4 v2 = ((const ushort4*)(xt + ((size_t)et2 * n + sc2) * 256))[lane];
    ushort4 v3 = ((const ushort4*)(xt + ((size_t)et3 * n + sc3) * 256))[lane];
    a0 += w0*b2f(v0.x) + w1*b2f(v1.x) + w2*b2f(v2.x) + w3*b2f(v3.x);
    a1 += w0*b2f(v0.y) + w1*b2f(v1.y) + w2*b2f(v2.y) + w3*b2f(v3.y);
    a2 += w0*b2f(v0.z) + w1*b2f(v1.z) + w2*b2f(v2.z) + w3*b2f(v3.z);
    a3 += w0*b2f(v0.w) + w1*b2f(v1.w) + w2*b2f(v2.w) + w3*b2f(v3.w);
  }
  for (; j < s1; ++j){
    int sc = es_src[j], et = es_et[j];
    float wv = a[j];
    ushort4 v = ((const ushort4*)(xt + ((size_t)et * n + sc) * 256))[lane];
    a0 = fmaf(wv, b2f(v.x), a0);
    a1 = fmaf(wv, b2f(v.y), a1);
    a2 = fmaf(wv, b2f(v.z), a2);
    a3 = fmaf(wv, b2f(v.w), a3);
  }
  ushort4 o;
  o.x = f2b(fmaxf(a0 * inv, 0.f)); o.y = f2b(fmaxf(a1 * inv, 0.f));
  o.z = f2b(fmaxf(a2 * inv, 0.f)); o.w = f2b(fmaxf(a3 * inv, 0.f));
  ((ushort4*)(hout + (size_t)node * H_))[lane] = o;
}

// ================= TransE scoring (wave per edge) =================
__global__ void score_kernel(const unsigned short* __restrict__ hb, const unsigned short* __restrict__ relb,
                             const int* __restrict__ src_a, const int* __restrict__ dst_a,
                             const int* __restrict__ et_a, float* __restrict__ out, int E){
  int e = blockIdx.x * 4 + (threadIdx.x >> 6);
  int lane = threadIdx.x & 63;
  if (e >= E) return;
  int s = src_a[e], d = dst_a[e], r = et_a[e];
  ushort4 a4 = ((const ushort4*)(hb + (size_t)s * H_))[lane];
  ushort4 b4 = ((const ushort4*)(hb + (size_t)d * H_))[lane];
  ushort4 r4 = ((const ushort4*)(relb + (size_t)r * H_))[lane];
  float sum = fabsf(b2f(a4.x) + b2f(r4.x) - b2f(b4.x))
            + fabsf(b2f(a4.y) + b2f(r4.y) - b2f(b4.y))
            + fabsf(b2f(a4.z) + b2f(r4.z) - b2f(b4.z))
            + fabsf(b2f(a4.w) + b2f(r4.w) - b2f(b4.w));
  #pragma unroll
  for (int o = 32; o; o >>= 1) sum += __shfl_xor(sum, o);
  if (!lane) out[e] = GAMMA_ - sum;
}

extern "C" void kernel_launch(void* const* d_in, const int* in_sizes, int n_in,
                              void* d_out, int out_size, void* d_ws, size_t ws_size,
                              hipStream_t stream){
  const float* x         = (const float*)d_in[0];
  const int*   edge_idx  = (const int*)d_in[1];
  const int*   edge_type = (const int*)d_in[2];
  const float* W1        = (const float*)d_in[3];
  const float* q1        = (const float*)d_in[4];
  const float* k1        = (const float*)d_in[5];
  const float* W2        = (const float*)d_in[6];
  const float* q2        = (const float*)d_in[7];
  const float* k2        = (const float*)d_in[8];
  const float* lin_w     = (const float*)d_in[9];
  const float* lin_b     = (const float*)d_in[10];
  const float* rel_bert  = (const float*)d_in[11];
  const float* rel_lin_w = (const float*)d_in[12];
  const float* rel_lin_b = (const float*)d_in[13];
  float* score = (float*)d_out;

  const int Nn = in_sizes[0] / H_;   // 10000
  const int E  = in_sizes[1] / 2;    // 320000
  const int* src_a = edge_idx;
  const int* dst_a = edge_idx + E;
  const int NBLK  = (Nn + 31) / 32;  // 313
  const int NBINS = NBLK * 1024;

  // workspace carve-up (256B aligned)
  char* ws = (char*)d_ws;
  size_t cur_off = 0;
  auto carve = [&](size_t bytes)->char*{
    char* p = ws + cur_off;
    cur_off += (bytes + 255) & ~(size_t)255;
    return p;
  };
  unsigned short* xt   = (unsigned short*)carve((size_t)Nn * R_ * H_ * 2);
  unsigned short* xb   = (unsigned short*)carve((size_t)Nn * H_ * 2);
  unsigned short* h1   = (unsigned short*)carve((size_t)Nn * H_ * 2);
  unsigned short* h2   = (unsigned short*)carve((size_t)Nn * H_ * 2);
  unsigned short* outb = (unsigned short*)carve((size_t)Nn * H_ * 2);
  unsigned short* Wt1  = (unsigned short*)carve((size_t)R_ * 65536 * 2);
  unsigned short* Wt2  = (unsigned short*)carve((size_t)R_ * 65536 * 2);
  unsigned short* linT = (unsigned short*)carve(65536 * 2);
  unsigned short* relb = (unsigned short*)carve(R_ * H_ * 2);
  float* wqkT1 = (float*)carve(64 * H_ * 4);
  float* wqkT2 = (float*)carve(64 * H_ * 4);
  float* qdot  = (float*)carve((size_t)Nn * R_ * 4);
  float* kdot  = (float*)carve((size_t)Nn * R_ * 4);
  int* cnt2    = (int*)carve((size_t)NBINS * 4);
  int* cur2    = (int*)carve((size_t)NBINS * 4);
  int* tot     = (int*)carve((size_t)NBLK * 4);
  int* baseA   = (int*)carve((size_t)(NBLK + 1) * 4);
  int* ps2     = (int*)carve((size_t)(NBINS + 1) * 4);
  int* es_src  = (int*)carve((size_t)E * 4);
  int* es_et   = (int*)carve((size_t)E * 4);
  float* attn  = (float*)carve((size_t)E * 4);
  (void)ws_size; (void)n_in; (void)out_size;

  const int mt = (Nn + 127) / 128;         // 79
  const int g_gemm = 64 * mt;              // 5056 gemm blocks (MODE 0)
  const int nqd = (Nn + 3) / 4;            // 2500 qdot/attn_agg blocks

  // prep block ranges
  const int n4 = Nn * H_ / 4;
  const int nb0 = (n4 + 255) / 256, nb_tw = 2048, nb_lin = 64, nb_wqk = 2048, nb_rel = 32;
  const int nb_hist = (E + 255) / 256;
  const int nprep = nb0 + 2 * nb_tw + nb_lin + 2 * nb_wqk + nb_rel + nb_hist;

  hipMemsetAsync(cnt2, 0, (size_t)NBINS * 4, stream);
  hipMemsetAsync(cur2, 0, (size_t)NBINS * 4, stream);

  prep_kernel<<<nprep, 256, 0, stream>>>(
      x, xb, n4, W1, Wt1, W2, Wt2, lin_w, linT,
      q1, k1, wqkT1, q2, k2, wqkT2,
      rel_bert, rel_lin_w, rel_lin_b, relb,
      dst_a, edge_type, cnt2, E,
      nb0, nb_tw, nb_lin, nb_wqk, nb_rel, nb_hist);

  totred_kernel<<<NBLK, 256, 0, stream>>>(cnt2, tot);
  scan_kernel<<<1, 1024, 0, stream>>>(tot, baseA, NBLK);
  ps2scan_kernel<<<NBLK, 256, 0, stream>>>(cnt2, baseA, ps2, NBLK, NBINS);
  scatter2_kernel<<<(E + 255) / 256, 256, 0, stream>>>(src_a, dst_a, edge_type, ps2, cur2, es_src, es_et, E);

  // ---- layer 1 ----
  gemmq_kernel<0><<<g_gemm + nqd, 256, 0, stream>>>(xb, Wt1, xt, nullptr, Nn, g_gemm, wqkT1, qdot, kdot);
  attn_agg_kernel<<<nqd, 256, 0, stream>>>(xt, qdot, kdot, ps2, es_src, es_et, attn, h1, Nn);

  // ---- layer 2 ----
  gemmq_kernel<0><<<g_gemm + nqd, 256, 0, stream>>>(h1, Wt2, xt, nullptr, Nn, g_gemm, wqkT2, qdot, kdot);
  attn_agg_kernel<<<nqd, 256, 0, stream>>>(xt, qdot, kdot, ps2, es_src, es_et, attn, h2, Nn);

  // ---- final linear + scoring ----
  gemmq_kernel<1><<<2 * mt, 256, 0, stream>>>(h2, linT, outb, lin_b, Nn, 2 * mt, nullptr, nullptr, nullptr);
  score_kernel<<<(E + 3) / 4, 256, 0, stream>>>(outb, relb, src_a, dst_a, edge_type, score, E);
}